// Round 1
// baseline (1498.284 us; speedup 1.0000x reference)
//
#include <hip/hip_runtime.h>
#include <hip/hip_bf16.h>

typedef __attribute__((ext_vector_type(4))) float f32x4;
typedef __attribute__((ext_vector_type(8))) short s16x8;
typedef __attribute__((ext_vector_type(4))) short s16x4;

#define MFMA_BF16 __builtin_amdgcn_mfma_f32_16x16x32_bf16

__device__ inline short f2bf(float f) {
  unsigned u = __float_as_uint(f);
  u = (u + 0x7FFFu + ((u >> 16) & 1u)) >> 16;
  return (short)u;
}
__device__ inline float bf2f(short s) {
  return __uint_as_float(((unsigned)(unsigned short)s) << 16);
}

// ---------------- RMSNorm: fp32 in -> bf16 out, one row (2048) per block ----
__global__ __launch_bounds__(256) void rmsnorm_kernel(
    const float* __restrict__ x, const float* __restrict__ w, short* __restrict__ out)
{
  size_t row = blockIdx.x;
  const float* xr = x + row * 2048;
  int base = threadIdx.x * 8;
  f32x4 a = *(const f32x4*)(xr + base);
  f32x4 b = *(const f32x4*)(xr + base + 4);
  float ss = a[0]*a[0] + a[1]*a[1] + a[2]*a[2] + a[3]*a[3]
           + b[0]*b[0] + b[1]*b[1] + b[2]*b[2] + b[3]*b[3];
  #pragma unroll
  for (int off = 1; off < 64; off <<= 1) ss += __shfl_xor(ss, off, 64);
  __shared__ float red[4];
  if ((threadIdx.x & 63) == 0) red[threadIdx.x >> 6] = ss;
  __syncthreads();
  float tot = red[0] + red[1] + red[2] + red[3];
  // w * x * DIM^-0.5 / sqrt(mean(x^2)+eps)
  float rn = rsqrtf(tot * (1.0f / 2048.0f) + 1e-6f) * 0.022097086912079608f;
  s16x8 o;
  #pragma unroll
  for (int j = 0; j < 4; ++j) {
    o[j]     = f2bf(a[j] * w[base + j] * rn);
    o[4 + j] = f2bf(b[j] * w[base + 4 + j] * rn);
  }
  *(s16x8*)(out + row * 2048 + base) = o;
}

// ---------------- GEMM: C[M,N] = A[M,K](bf16) * Bw[N,K]^T(fp32, cvt in staging)
// 128x128 tile, BK=32, 4 waves (2x2), wave tile 64x64 = 4x4 16x16x32 MFMA frags.
// MODE 0: store bf16 C.  MODE 1: store fp32 C = acc + resid.
template <int MODE>
__global__ __launch_bounds__(256, 2) void gemm_bt_kernel(
    const short* __restrict__ A, const float* __restrict__ Bw,
    void* __restrict__ Cv, const float* __restrict__ resid,
    int M, int N, int K)
{
  __shared__ short As[128 * 32];
  __shared__ short Bs[128 * 32];
  int tid = threadIdx.x;
  int lane = tid & 63;
  int w = tid >> 6;
  int r = lane & 15, g = lane >> 4;
  int wr = w >> 1, wc = w & 1;
  size_t row0 = (size_t)blockIdx.y * 128;
  size_t col0 = (size_t)blockIdx.x * 128;

  f32x4 acc[4][4];
  #pragma unroll
  for (int i = 0; i < 4; ++i)
    #pragma unroll
    for (int j = 0; j < 4; ++j) acc[i][j] = (f32x4){0.f, 0.f, 0.f, 0.f};

  const short* Ablk = A + row0 * K;
  const float* Bblk = Bw + col0 * K;

  for (int k0 = 0; k0 < K; k0 += 32) {
    // A: global -> LDS direct, 16B/lane, linear dest (2 insts cover 128x32 bf16)
    #pragma unroll
    for (int i = 0; i < 2; ++i) {
      int chunk = i * 256 + tid;          // 16B chunk index
      int arow = chunk >> 2;
      int akk = (chunk & 3) << 3;
      __builtin_amdgcn_global_load_lds(
          (const __attribute__((address_space(1))) unsigned int*)(Ablk + (size_t)arow * K + k0 + akk),
          (__attribute__((address_space(3))) unsigned int*)(&As[chunk * 8]),
          16, 0, 0);
    }
    // B: fp32 global -> regs -> cvt bf16 -> LDS (16 elems/thread)
    #pragma unroll
    for (int c = 0; c < 4; ++c) {
      int e = c * 1024 + tid * 4;
      int brow = e >> 5;
      int bkk = e & 31;
      f32x4 f = *(const f32x4*)(Bblk + (size_t)brow * K + k0 + bkk);
      s16x4 sv;
      sv[0] = f2bf(f[0]); sv[1] = f2bf(f[1]); sv[2] = f2bf(f[2]); sv[3] = f2bf(f[3]);
      *(s16x4*)(&Bs[e]) = sv;
    }
    __syncthreads();
    s16x8 af[4], bfr[4];
    #pragma unroll
    for (int mm = 0; mm < 4; ++mm)
      af[mm] = *(const s16x8*)(&As[(wr * 64 + mm * 16 + r) * 32 + g * 8]);
    #pragma unroll
    for (int nn = 0; nn < 4; ++nn)
      bfr[nn] = *(const s16x8*)(&Bs[(wc * 64 + nn * 16 + r) * 32 + g * 8]);
    #pragma unroll
    for (int mm = 0; mm < 4; ++mm)
      #pragma unroll
      for (int nn = 0; nn < 4; ++nn)
        acc[mm][nn] = MFMA_BF16(af[mm], bfr[nn], acc[mm][nn], 0, 0, 0);
    __syncthreads();
  }

  // C/D frag layout: col = lane&15, row = (lane>>4)*4 + j   [m89-verified]
  #pragma unroll
  for (int mm = 0; mm < 4; ++mm) {
    #pragma unroll
    for (int nn = 0; nn < 4; ++nn) {
      #pragma unroll
      for (int j = 0; j < 4; ++j) {
        size_t rr = row0 + wr * 64 + mm * 16 + g * 4 + j;
        size_t cc = col0 + wc * 64 + nn * 16 + r;
        if constexpr (MODE == 0) {
          ((short*)Cv)[rr * (size_t)N + cc] = f2bf(acc[mm][nn][j]);
        } else {
          ((float*)Cv)[rr * (size_t)N + cc] = acc[mm][nn][j] + resid[rr * (size_t)N + cc];
        }
      }
    }
  }
}

// ---------------- V transpose: [B*S,128] -> [B][128][S] ---------------------
__global__ __launch_bounds__(256) void transpose_v_kernel(
    const short* __restrict__ v, short* __restrict__ vt)
{
  __shared__ short t[64][65];
  int b = blockIdx.z;
  int s0 = blockIdx.x * 64;
  int d0 = blockIdx.y * 64;
  int tid = threadIdx.x;
  #pragma unroll
  for (int i = 0; i < 16; ++i) {
    int e = i * 256 + tid;
    int sr = e >> 6, dc = e & 63;
    t[sr][dc] = v[(size_t)(b * 2048 + s0 + sr) * 128 + d0 + dc];
  }
  __syncthreads();
  #pragma unroll
  for (int i = 0; i < 16; ++i) {
    int e = i * 256 + tid;
    int dr = e >> 6, sc = e & 63;
    vt[(size_t)b * 128 * 2048 + (size_t)(d0 + dr) * 2048 + s0 + sc] = t[sc][dr];
  }
}

// ---------------- Flash attention (MQA), 16 q-rows/wave, KVBLK=32 -----------
__global__ __launch_bounds__(256, 2) void attn_kernel(
    const short* __restrict__ q, const short* __restrict__ k,
    const short* __restrict__ vt, short* __restrict__ out)
{
  const int S = 2048;
  int w = threadIdx.x >> 6;
  int lane = threadIdx.x & 63;
  int r = lane & 15, g = lane >> 4;
  int h = blockIdx.y, b = blockIdx.z;
  int qrow0 = blockIdx.x * 64 + w * 16;

  __shared__ short P[4][16][40];   // per-wave P tile, padded stride 40

  const short* qbase = q + ((size_t)(b * S + qrow0 + r)) * 2048 + h * 128;
  s16x8 qa[4];
  #pragma unroll
  for (int dc = 0; dc < 4; ++dc) qa[dc] = *(const s16x8*)(qbase + dc * 32 + g * 8);

  f32x4 o[8];
  #pragma unroll
  for (int dt = 0; dt < 8; ++dt) o[dt] = (f32x4){0.f, 0.f, 0.f, 0.f};
  float m[4], l[4];
  #pragma unroll
  for (int j = 0; j < 4; ++j) { m[j] = -1e30f; l[j] = 0.f; }

  const short* kbase = k + (size_t)b * S * 128;
  const short* vbase = vt + (size_t)b * 128 * S;

  for (int kv0 = 0; kv0 < S; kv0 += 32) {
    f32x4 s0 = {0.f, 0.f, 0.f, 0.f}, s1 = {0.f, 0.f, 0.f, 0.f};
    #pragma unroll
    for (int dc = 0; dc < 4; ++dc) {
      s16x8 kb0 = *(const s16x8*)(kbase + (size_t)(kv0 + r) * 128 + dc * 32 + g * 8);
      s16x8 kb1 = *(const s16x8*)(kbase + (size_t)(kv0 + 16 + r) * 128 + dc * 32 + g * 8);
      s0 = MFMA_BF16(qa[dc], kb0, s0, 0, 0, 0);
      s1 = MFMA_BF16(qa[dc], kb1, s1, 0, 0, 0);
    }
    const float sc = 0.08838834764831845f;  // 1/sqrt(128)
    float mx[4];
    #pragma unroll
    for (int j = 0; j < 4; ++j) {
      s0[j] *= sc; s1[j] *= sc;
      mx[j] = fmaxf(s0[j], s1[j]);
    }
    #pragma unroll
    for (int off = 1; off < 16; off <<= 1) {
      #pragma unroll
      for (int j = 0; j < 4; ++j) mx[j] = fmaxf(mx[j], __shfl_xor(mx[j], off, 64));
    }
    float alpha[4], rs[4], p0[4], p1[4];
    #pragma unroll
    for (int j = 0; j < 4; ++j) {
      float mn = fmaxf(m[j], mx[j]);
      alpha[j] = __expf(m[j] - mn);
      p0[j] = __expf(s0[j] - mn);
      p1[j] = __expf(s1[j] - mn);
      m[j] = mn;
      rs[j] = p0[j] + p1[j];
    }
    #pragma unroll
    for (int off = 1; off < 16; off <<= 1) {
      #pragma unroll
      for (int j = 0; j < 4; ++j) rs[j] += __shfl_xor(rs[j], off, 64);
    }
    #pragma unroll
    for (int j = 0; j < 4; ++j) l[j] = l[j] * alpha[j] + rs[j];
    // P (16x32) via per-wave LDS to become the PV A-operand
    #pragma unroll
    for (int j = 0; j < 4; ++j) {
      P[w][g * 4 + j][r]      = f2bf(p0[j]);
      P[w][g * 4 + j][16 + r] = f2bf(p1[j]);
    }
    asm volatile("s_waitcnt lgkmcnt(0)" ::: "memory");
    s16x8 pa = *(const s16x8*)&P[w][r][g * 8];
    #pragma unroll
    for (int dt = 0; dt < 8; ++dt) {
      #pragma unroll
      for (int j = 0; j < 4; ++j) o[dt][j] *= alpha[j];
    }
    #pragma unroll
    for (int dt = 0; dt < 8; ++dt) {
      s16x8 vb = *(const s16x8*)(vbase + (size_t)(dt * 16 + r) * S + kv0 + g * 8);
      o[dt] = MFMA_BF16(pa, vb, o[dt], 0, 0, 0);
    }
  }
  float rl[4];
  #pragma unroll
  for (int j = 0; j < 4; ++j) rl[j] = 1.0f / l[j];
  short* ob = out + ((size_t)(b * S + qrow0)) * 2048 + h * 128;
  #pragma unroll
  for (int dt = 0; dt < 8; ++dt)
    #pragma unroll
    for (int j = 0; j < 4; ++j)
      ob[(size_t)(g * 4 + j) * 2048 + dt * 16 + r] = f2bf(o[dt][j] * rl[j]);
}

// ---------------- SwiGLU elementwise: p = silu(g) * u (in-place into g ok) --
__global__ __launch_bounds__(256) void silu_mul_kernel(
    const short* __restrict__ g, const short* __restrict__ u, short* __restrict__ p)
{
  size_t idx = ((size_t)blockIdx.x * 256 + threadIdx.x) * 8;
  s16x8 gv = *(const s16x8*)(g + idx);
  s16x8 uv = *(const s16x8*)(u + idx);
  s16x8 o;
  #pragma unroll
  for (int j = 0; j < 8; ++j) {
    float gf = bf2f(gv[j]);
    float uf = bf2f(uv[j]);
    float s = gf / (1.0f + __expf(-gf));
    o[j] = f2bf(s * uf);
  }
  *(s16x8*)(p + idx) = o;
}

extern "C" void kernel_launch(void* const* d_in, const int* in_sizes, int n_in,
                              void* d_out, int out_size, void* d_ws, size_t ws_size,
                              hipStream_t stream) {
  const float* x   = (const float*)d_in[0];
  const float* n1w = (const float*)d_in[1];
  const float* wq  = (const float*)d_in[2];
  const float* wk  = (const float*)d_in[3];
  const float* wv  = (const float*)d_in[4];
  const float* wo  = (const float*)d_in[5];
  const float* n2w = (const float*)d_in[6];
  const float* w1  = (const float*)d_in[7];
  const float* w2  = (const float*)d_in[8];
  const float* w3  = (const float*)d_in[9];
  float* out = (float*)d_out;
  char* ws = (char*)d_ws;
  const size_t MB = 1ull << 20;
  short* h1   = (short*)(ws);              // 16 MB  (also reused as h2)
  short* qb   = (short*)(ws + 16 * MB);    // 16 MB
  short* kbuf = (short*)(ws + 32 * MB);    //  1 MB
  short* vbuf = (short*)(ws + 33 * MB);    //  1 MB
  short* vtb  = (short*)(ws + 34 * MB);    //  1 MB
  short* attn = (short*)(ws + 35 * MB);    // 16 MB
  float* xmid = (float*)(ws + 51 * MB);    // 32 MB
  short* gbuf = (short*)(ws + 83 * MB);    // 64 MB
  short* ubuf = (short*)(ws + 147 * MB);   // 64 MB -> 211 MB total

  rmsnorm_kernel<<<4096, 256, 0, stream>>>(x, n1w, h1);
  gemm_bt_kernel<0><<<dim3(16, 32), 256, 0, stream>>>(h1, wq, qb, nullptr, 4096, 2048, 2048);
  gemm_bt_kernel<0><<<dim3(1, 32), 256, 0, stream>>>(h1, wk, kbuf, nullptr, 4096, 128, 2048);
  gemm_bt_kernel<0><<<dim3(1, 32), 256, 0, stream>>>(h1, wv, vbuf, nullptr, 4096, 128, 2048);
  transpose_v_kernel<<<dim3(32, 2, 2), 256, 0, stream>>>(vbuf, vtb);
  attn_kernel<<<dim3(32, 16, 2), 256, 0, stream>>>(qb, kbuf, vtb, attn);
  gemm_bt_kernel<1><<<dim3(16, 32), 256, 0, stream>>>(attn, wo, xmid, x, 4096, 2048, 2048);
  rmsnorm_kernel<<<4096, 256, 0, stream>>>(xmid, n2w, h1);
  gemm_bt_kernel<0><<<dim3(64, 32), 256, 0, stream>>>(h1, w1, gbuf, nullptr, 4096, 8192, 2048);
  gemm_bt_kernel<0><<<dim3(64, 32), 256, 0, stream>>>(h1, w3, ubuf, nullptr, 4096, 8192, 2048);
  silu_mul_kernel<<<16384, 256, 0, stream>>>(gbuf, ubuf, gbuf);
  gemm_bt_kernel<1><<<dim3(16, 32), 256, 0, stream>>>(gbuf, w2, out, xmid, 4096, 2048, 8192);
}

// Round 2
// 1241.337 us; speedup vs baseline: 1.2070x; 1.2070x over previous
//
#include <hip/hip_runtime.h>
#include <hip/hip_bf16.h>

typedef __attribute__((ext_vector_type(4))) float f32x4;
typedef __attribute__((ext_vector_type(8))) short s16x8;
typedef __attribute__((ext_vector_type(4))) short s16x4;

#define MFMA_BF16 __builtin_amdgcn_mfma_f32_16x16x32_bf16

__device__ inline short f2bf(float f) {
  unsigned u = __float_as_uint(f);
  u = (u + 0x7FFFu + ((u >> 16) & 1u)) >> 16;
  return (short)u;
}
__device__ inline float bf2f(short s) {
  return __uint_as_float(((unsigned)(unsigned short)s) << 16);
}

// ---------------- fp32 -> bf16 weight conversion, 8 elems/thread ------------
__global__ __launch_bounds__(256) void cvt_kernel(
    const float* __restrict__ in, short* __restrict__ out, int n)
{
  int idx = (blockIdx.x * 256 + threadIdx.x) * 8;
  if (idx >= n) return;
  f32x4 a = *(const f32x4*)(in + idx);
  f32x4 b = *(const f32x4*)(in + idx + 4);
  s16x8 o;
  #pragma unroll
  for (int j = 0; j < 4; ++j) { o[j] = f2bf(a[j]); o[4 + j] = f2bf(b[j]); }
  *(s16x8*)(out + idx) = o;
}

// ---------------- RMSNorm: fp32 in -> bf16 out, one row (2048) per block ----
__global__ __launch_bounds__(256) void rmsnorm_kernel(
    const float* __restrict__ x, const float* __restrict__ w, short* __restrict__ out)
{
  size_t row = blockIdx.x;
  const float* xr = x + row * 2048;
  int base = threadIdx.x * 8;
  f32x4 a = *(const f32x4*)(xr + base);
  f32x4 b = *(const f32x4*)(xr + base + 4);
  float ss = a[0]*a[0] + a[1]*a[1] + a[2]*a[2] + a[3]*a[3]
           + b[0]*b[0] + b[1]*b[1] + b[2]*b[2] + b[3]*b[3];
  #pragma unroll
  for (int off = 1; off < 64; off <<= 1) ss += __shfl_xor(ss, off, 64);
  __shared__ float red[4];
  if ((threadIdx.x & 63) == 0) red[threadIdx.x >> 6] = ss;
  __syncthreads();
  float tot = red[0] + red[1] + red[2] + red[3];
  float rn = rsqrtf(tot * (1.0f / 2048.0f) + 1e-6f) * 0.022097086912079608f;
  f32x4 wa = *(const f32x4*)(w + base);
  f32x4 wb = *(const f32x4*)(w + base + 4);
  s16x8 o;
  #pragma unroll
  for (int j = 0; j < 4; ++j) {
    o[j]     = f2bf(a[j] * wa[j] * rn);
    o[4 + j] = f2bf(b[j] * wb[j] * rn);
  }
  *(s16x8*)(out + row * 2048 + base) = o;
}

// ---------------- GEMM: C[M,N] = A[M,K](bf16) * B[N,K]^T(bf16) --------------
// m97 structure: 128x128 tile, BK=32, 4 waves (2x2), global_load_lds both sides.
// MODE 0: store bf16 C.
// MODE 1: store fp32 C = acc + resid(fp32).    (resid may alias Cv)
// MODE 2: Cv bf16 in/out: C = silu(Cprev) * acc  (SwiGLU fuse; w1 result in Cv)
template <int MODE>
__global__ __launch_bounds__(256, 2) void gemm_bt_kernel(
    const short* __restrict__ A, const short* __restrict__ B,
    void* __restrict__ Cv, const float* __restrict__ resid,
    int M, int N, int K)
{
  __shared__ short As[128 * 32];
  __shared__ short Bs[128 * 32];
  int tid = threadIdx.x;
  int lane = tid & 63;
  int w = tid >> 6;
  int r = lane & 15, g = lane >> 4;
  int wr = w >> 1, wc = w & 1;
  size_t row0 = (size_t)blockIdx.y * 128;
  size_t col0 = (size_t)blockIdx.x * 128;

  f32x4 acc[4][4];
  #pragma unroll
  for (int i = 0; i < 4; ++i)
    #pragma unroll
    for (int j = 0; j < 4; ++j) acc[i][j] = (f32x4){0.f, 0.f, 0.f, 0.f};

  const short* Ablk = A + row0 * K;
  const short* Bblk = B + col0 * K;
  int arow = tid >> 2;          // 16B chunk -> row, kk
  int akk = (tid & 3) << 3;

  for (int k0 = 0; k0 < K; k0 += 32) {
    #pragma unroll
    for (int i = 0; i < 2; ++i) {
      int chunk = i * 256 + tid;
      int rr = i * 64 + arow;
      __builtin_amdgcn_global_load_lds(
          (const __attribute__((address_space(1))) unsigned int*)(Ablk + (size_t)rr * K + k0 + akk),
          (__attribute__((address_space(3))) unsigned int*)(&As[chunk * 8]), 16, 0, 0);
      __builtin_amdgcn_global_load_lds(
          (const __attribute__((address_space(1))) unsigned int*)(Bblk + (size_t)rr * K + k0 + akk),
          (__attribute__((address_space(3))) unsigned int*)(&Bs[chunk * 8]), 16, 0, 0);
    }
    __syncthreads();
    s16x8 af[4], bfr[4];
    #pragma unroll
    for (int mm = 0; mm < 4; ++mm)
      af[mm] = *(const s16x8*)(&As[(wr * 64 + mm * 16 + r) * 32 + g * 8]);
    #pragma unroll
    for (int nn = 0; nn < 4; ++nn)
      bfr[nn] = *(const s16x8*)(&Bs[(wc * 64 + nn * 16 + r) * 32 + g * 8]);
    #pragma unroll
    for (int mm = 0; mm < 4; ++mm)
      #pragma unroll
      for (int nn = 0; nn < 4; ++nn)
        acc[mm][nn] = MFMA_BF16(af[mm], bfr[nn], acc[mm][nn], 0, 0, 0);
    __syncthreads();
  }

  // C/D frag: col = lane&15, row = (lane>>4)*4 + j
  #pragma unroll
  for (int mm = 0; mm < 4; ++mm) {
    #pragma unroll
    for (int nn = 0; nn < 4; ++nn) {
      #pragma unroll
      for (int j = 0; j < 4; ++j) {
        size_t rr = row0 + wr * 64 + mm * 16 + g * 4 + j;
        size_t cc = col0 + wc * 64 + nn * 16 + r;
        size_t idx = rr * (size_t)N + cc;
        if constexpr (MODE == 0) {
          ((short*)Cv)[idx] = f2bf(acc[mm][nn][j]);
        } else if constexpr (MODE == 1) {
          ((float*)Cv)[idx] = acc[mm][nn][j] + resid[idx];
        } else {
          short* gp = (short*)Cv;
          float gv = bf2f(gp[idx]);
          float sg = gv / (1.0f + __expf(-gv));
          gp[idx] = f2bf(sg * acc[mm][nn][j]);
        }
      }
    }
  }
}

// ---------------- V transpose: kv[B*S,256] cols 128..255 -> [B][128][S] -----
__global__ __launch_bounds__(256) void transpose_v_kernel(
    const short* __restrict__ kv, short* __restrict__ vt)
{
  __shared__ short t[64][65];
  int b = blockIdx.z;
  int s0 = blockIdx.x * 64;
  int d0 = blockIdx.y * 64;
  int tid = threadIdx.x;
  #pragma unroll
  for (int i = 0; i < 16; ++i) {
    int e = i * 256 + tid;
    int sr = e >> 6, dc = e & 63;
    t[sr][dc] = kv[(size_t)(b * 2048 + s0 + sr) * 256 + 128 + d0 + dc];
  }
  __syncthreads();
  #pragma unroll
  for (int i = 0; i < 16; ++i) {
    int e = i * 256 + tid;
    int dr = e >> 6, sc = e & 63;
    vt[(size_t)b * 128 * 2048 + (size_t)(d0 + dr) * 2048 + s0 + sc] = t[sc][dr];
  }
}

// ---------------- Flash attention (MQA), wave-split KV ----------------------
// Block: 4 waves, ALL handle the same 16 q-rows; wave w covers kv [w*512,(w+1)*512).
// Epilogue: (m,l,o) combine across waves via LDS.
__global__ __launch_bounds__(256) void attn_kernel(
    const short* __restrict__ q, const short* __restrict__ kv,
    const short* __restrict__ vt, short* __restrict__ out)
{
  const int S = 2048;
  int tid = threadIdx.x;
  int w = tid >> 6;
  int lane = tid & 63;
  int r = lane & 15, g = lane >> 4;
  int h = blockIdx.y, b = blockIdx.z;
  int qrow0 = blockIdx.x * 16;

  __shared__ float Lo[4][16][132];
  __shared__ float Lm[4][16], Ll[4][16], Smg[16], Sil[16];
  __shared__ short P[4][16][40];

  const short* qbase = q + ((size_t)(b * S + qrow0 + r)) * 2048 + h * 128;
  s16x8 qa[4];
  #pragma unroll
  for (int dc = 0; dc < 4; ++dc) qa[dc] = *(const s16x8*)(qbase + dc * 32 + g * 8);

  f32x4 o[8];
  #pragma unroll
  for (int dt = 0; dt < 8; ++dt) o[dt] = (f32x4){0.f, 0.f, 0.f, 0.f};
  float m[4], l[4];
  #pragma unroll
  for (int j = 0; j < 4; ++j) { m[j] = -1e30f; l[j] = 0.f; }

  const short* kbase = kv + (size_t)b * S * 256;   // row stride 256, K in cols 0..127
  const short* vbase = vt + (size_t)b * 128 * S;
  int kv0 = w * 512;

  // preload first K tile (2x16 kv rows x 128 d)
  s16x8 kc[8];
  #pragma unroll
  for (int dc = 0; dc < 4; ++dc) {
    kc[dc]     = *(const s16x8*)(kbase + (size_t)(kv0 + r) * 256 + dc * 32 + g * 8);
    kc[4 + dc] = *(const s16x8*)(kbase + (size_t)(kv0 + 16 + r) * 256 + dc * 32 + g * 8);
  }

  for (int it = 0; it < 16; ++it) {
    int kvc = kv0 + it * 32;
    // V loads issued early: land during QK + softmax
    s16x8 vb[8];
    #pragma unroll
    for (int dt = 0; dt < 8; ++dt)
      vb[dt] = *(const s16x8*)(vbase + (size_t)(dt * 16 + r) * S + kvc + g * 8);
    f32x4 s0 = {0.f, 0.f, 0.f, 0.f}, s1 = {0.f, 0.f, 0.f, 0.f};
    #pragma unroll
    for (int dc = 0; dc < 4; ++dc) {
      s0 = MFMA_BF16(qa[dc], kc[dc], s0, 0, 0, 0);
      s1 = MFMA_BF16(qa[dc], kc[4 + dc], s1, 0, 0, 0);
    }
    // prefetch next K tile; latency hides under softmax
    if (it < 15) {
      int kvn = kvc + 32;
      #pragma unroll
      for (int dc = 0; dc < 4; ++dc) {
        kc[dc]     = *(const s16x8*)(kbase + (size_t)(kvn + r) * 256 + dc * 32 + g * 8);
        kc[4 + dc] = *(const s16x8*)(kbase + (size_t)(kvn + 16 + r) * 256 + dc * 32 + g * 8);
      }
    }
    const float sc = 0.08838834764831845f;  // 1/sqrt(128)
    float mx[4];
    #pragma unroll
    for (int j = 0; j < 4; ++j) {
      s0[j] *= sc; s1[j] *= sc;
      mx[j] = fmaxf(s0[j], s1[j]);
    }
    #pragma unroll
    for (int off = 1; off < 16; off <<= 1) {
      #pragma unroll
      for (int j = 0; j < 4; ++j) mx[j] = fmaxf(mx[j], __shfl_xor(mx[j], off, 64));
    }
    float alpha[4], rs[4], p0[4], p1[4];
    #pragma unroll
    for (int j = 0; j < 4; ++j) {
      float mn = fmaxf(m[j], mx[j]);
      alpha[j] = __expf(m[j] - mn);
      p0[j] = __expf(s0[j] - mn);
      p1[j] = __expf(s1[j] - mn);
      m[j] = mn;
      rs[j] = p0[j] + p1[j];
    }
    #pragma unroll
    for (int off = 1; off < 16; off <<= 1) {
      #pragma unroll
      for (int j = 0; j < 4; ++j) rs[j] += __shfl_xor(rs[j], off, 64);
    }
    #pragma unroll
    for (int j = 0; j < 4; ++j) l[j] = l[j] * alpha[j] + rs[j];
    #pragma unroll
    for (int j = 0; j < 4; ++j) {
      P[w][g * 4 + j][r]      = f2bf(p0[j]);
      P[w][g * 4 + j][16 + r] = f2bf(p1[j]);
    }
    asm volatile("s_waitcnt lgkmcnt(0)" ::: "memory");
    __builtin_amdgcn_sched_barrier(0);
    s16x8 pa = *(const s16x8*)&P[w][r][g * 8];
    #pragma unroll
    for (int dt = 0; dt < 8; ++dt) {
      #pragma unroll
      for (int j = 0; j < 4; ++j) o[dt][j] *= alpha[j];
    }
    #pragma unroll
    for (int dt = 0; dt < 8; ++dt)
      o[dt] = MFMA_BF16(pa, vb[dt], o[dt], 0, 0, 0);
  }

  // ---- combine 4 waves' partial (m, l, o) ----
  if (r == 0) {
    #pragma unroll
    for (int j = 0; j < 4; ++j) { Lm[w][g * 4 + j] = m[j]; Ll[w][g * 4 + j] = l[j]; }
  }
  __syncthreads();
  if (tid < 16) {
    int row = tid;
    float mg = fmaxf(fmaxf(Lm[0][row], Lm[1][row]), fmaxf(Lm[2][row], Lm[3][row]));
    float lg = Ll[0][row] * __expf(Lm[0][row] - mg)
             + Ll[1][row] * __expf(Lm[1][row] - mg)
             + Ll[2][row] * __expf(Lm[2][row] - mg)
             + Ll[3][row] * __expf(Lm[3][row] - mg);
    Smg[row] = mg;
    Sil[row] = 1.0f / lg;
  }
  __syncthreads();
  float scl[4];
  #pragma unroll
  for (int j = 0; j < 4; ++j) scl[j] = __expf(m[j] - Smg[g * 4 + j]);
  #pragma unroll
  for (int dt = 0; dt < 8; ++dt)
    #pragma unroll
    for (int j = 0; j < 4; ++j)
      Lo[w][g * 4 + j][dt * 16 + r] = o[dt][j] * scl[j];
  __syncthreads();
  int row = tid >> 4, c0 = (tid & 15) * 8;
  float inv = Sil[row];
  s16x8 ov;
  #pragma unroll
  for (int c = 0; c < 8; ++c) {
    float s = Lo[0][row][c0 + c] + Lo[1][row][c0 + c]
            + Lo[2][row][c0 + c] + Lo[3][row][c0 + c];
    ov[c] = f2bf(s * inv);
  }
  *(s16x8*)(out + (size_t)(b * S + qrow0 + row) * 2048 + h * 128 + c0) = ov;
}

extern "C" void kernel_launch(void* const* d_in, const int* in_sizes, int n_in,
                              void* d_out, int out_size, void* d_ws, size_t ws_size,
                              hipStream_t stream) {
  const float* x   = (const float*)d_in[0];
  const float* n1w = (const float*)d_in[1];
  const float* wq  = (const float*)d_in[2];
  const float* wk  = (const float*)d_in[3];
  const float* wv  = (const float*)d_in[4];
  const float* wo  = (const float*)d_in[5];
  const float* n2w = (const float*)d_in[6];
  const float* w1  = (const float*)d_in[7];
  const float* w2  = (const float*)d_in[8];
  const float* w3  = (const float*)d_in[9];
  float* out = (float*)d_out;   // doubles as fp32 xmid buffer
  char* ws = (char*)d_ws;
  const size_t MB = 1ull << 20;
  // persistent bf16 weights: 113 MB
  short* wqb  = (short*)(ws);              //  8 MB [2048,2048]
  short* wob  = (short*)(ws + 8 * MB);     //  8 MB [2048,2048]
  short* w1b  = (short*)(ws + 16 * MB);    // 32 MB [8192,2048]
  short* w2b  = (short*)(ws + 48 * MB);    // 32 MB [2048,8192]
  short* w3b  = (short*)(ws + 80 * MB);    // 32 MB [8192,2048]
  short* wkvb = (short*)(ws + 112 * MB);   //  1 MB [256,2048] (wk rows 0-127, wv 128-255)
  // activations
  short* h1   = (short*)(ws + 113 * MB);   // 16 MB; also reused as attn-out
  short* gbuf = (short*)(ws + 129 * MB);   // 64 MB [4096,8192]; overlays qb/kvb/vtb
  short* qb   = (short*)(ws + 129 * MB);   // 16 MB (dead before gbuf written)
  short* kvb  = (short*)(ws + 145 * MB);   //  2 MB [4096,256]
  short* vtb  = (short*)(ws + 147 * MB);   //  1 MB [2][128][2048]
  // total: 193 MB

  // weight conversion (one-time per launch)
  cvt_kernel<<<2048, 256, 0, stream>>>(wq, wqb, 4194304);
  cvt_kernel<<<128,  256, 0, stream>>>(wk, wkvb, 262144);
  cvt_kernel<<<128,  256, 0, stream>>>(wv, wkvb + 262144, 262144);
  cvt_kernel<<<2048, 256, 0, stream>>>(wo, wob, 4194304);
  cvt_kernel<<<8192, 256, 0, stream>>>(w1, w1b, 16777216);
  cvt_kernel<<<8192, 256, 0, stream>>>(w2, w2b, 16777216);
  cvt_kernel<<<8192, 256, 0, stream>>>(w3, w3b, 16777216);

  rmsnorm_kernel<<<4096, 256, 0, stream>>>(x, n1w, h1);
  gemm_bt_kernel<0><<<dim3(16, 32), 256, 0, stream>>>(h1, wqb, qb, nullptr, 4096, 2048, 2048);
  gemm_bt_kernel<0><<<dim3(2, 32), 256, 0, stream>>>(h1, wkvb, kvb, nullptr, 4096, 256, 2048);
  transpose_v_kernel<<<dim3(32, 2, 2), 256, 0, stream>>>(kvb, vtb);
  attn_kernel<<<dim3(128, 16, 2), 256, 0, stream>>>(qb, kvb, vtb, h1);
  gemm_bt_kernel<1><<<dim3(16, 32), 256, 0, stream>>>(h1, wob, out, x, 4096, 2048, 2048);
  rmsnorm_kernel<<<4096, 256, 0, stream>>>(out, n2w, h1);
  gemm_bt_kernel<0><<<dim3(64, 32), 256, 0, stream>>>(h1, w1b, gbuf, nullptr, 4096, 8192, 2048);
  gemm_bt_kernel<2><<<dim3(64, 32), 256, 0, stream>>>(h1, w3b, gbuf, nullptr, 4096, 8192, 2048);
  gemm_bt_kernel<1><<<dim3(16, 32), 256, 0, stream>>>(gbuf, w2b, out, out, 4096, 2048, 8192);
}

// Round 3
// 1238.053 us; speedup vs baseline: 1.2102x; 1.0027x over previous
//
#include <hip/hip_runtime.h>
#include <hip/hip_bf16.h>

typedef __attribute__((ext_vector_type(4))) float f32x4;
typedef __attribute__((ext_vector_type(8))) short s16x8;
typedef __attribute__((ext_vector_type(4))) short s16x4;
typedef __attribute__((ext_vector_type(2))) short s16x2;

#define MFMA_BF16 __builtin_amdgcn_mfma_f32_16x16x32_bf16

__device__ inline short f2bf(float f) {
  unsigned u = __float_as_uint(f);
  u = (u + 0x7FFFu + ((u >> 16) & 1u)) >> 16;
  return (short)u;
}
__device__ inline float bf2f(short s) {
  return __uint_as_float(((unsigned)(unsigned short)s) << 16);
}

// DPP cross-lane over each 16-lane row (VALU pipe, ~3cy/step vs ~50-100cy ds ops)
#define DPPF(x, ctrl) __int_as_float(__builtin_amdgcn_update_dpp( \
    __float_as_int(x), __float_as_int(x), ctrl, 0xF, 0xF, false))
__device__ inline float rowmax16(float x) {
  x = fmaxf(x, DPPF(x, 0xB1));   // quad xor1
  x = fmaxf(x, DPPF(x, 0x4E));   // quad xor2
  x = fmaxf(x, DPPF(x, 0x124));  // row_ror:4
  x = fmaxf(x, DPPF(x, 0x128));  // row_ror:8
  return x;
}
__device__ inline float rowsum16(float x) {
  x += DPPF(x, 0xB1);
  x += DPPF(x, 0x4E);
  x += DPPF(x, 0x124);
  x += DPPF(x, 0x128);
  return x;
}

// ---------------- fp32 -> bf16 conversion (optional uniform scale) ----------
__global__ __launch_bounds__(256) void cvt_kernel(
    const float* __restrict__ in, short* __restrict__ out, int n, float scale)
{
  int idx = (blockIdx.x * 256 + threadIdx.x) * 8;
  if (idx >= n) return;
  f32x4 a = *(const f32x4*)(in + idx);
  f32x4 b = *(const f32x4*)(in + idx + 4);
  s16x8 o;
  #pragma unroll
  for (int j = 0; j < 4; ++j) { o[j] = f2bf(a[j] * scale); o[4 + j] = f2bf(b[j] * scale); }
  *(s16x8*)(out + idx) = o;
}

// ---------------- RMSNorm: fp32 in -> bf16 out, one row (2048) per block ----
__global__ __launch_bounds__(256) void rmsnorm_kernel(
    const float* __restrict__ x, const float* __restrict__ w, short* __restrict__ out)
{
  size_t row = blockIdx.x;
  const float* xr = x + row * 2048;
  int base = threadIdx.x * 8;
  f32x4 a = *(const f32x4*)(xr + base);
  f32x4 b = *(const f32x4*)(xr + base + 4);
  float ss = a[0]*a[0] + a[1]*a[1] + a[2]*a[2] + a[3]*a[3]
           + b[0]*b[0] + b[1]*b[1] + b[2]*b[2] + b[3]*b[3];
  #pragma unroll
  for (int off = 1; off < 64; off <<= 1) ss += __shfl_xor(ss, off, 64);
  __shared__ float red[4];
  if ((threadIdx.x & 63) == 0) red[threadIdx.x >> 6] = ss;
  __syncthreads();
  float tot = red[0] + red[1] + red[2] + red[3];
  float rn = rsqrtf(tot * (1.0f / 2048.0f) + 1e-6f) * 0.022097086912079608f;
  f32x4 wa = *(const f32x4*)(w + base);
  f32x4 wb = *(const f32x4*)(w + base + 4);
  s16x8 o;
  #pragma unroll
  for (int j = 0; j < 4; ++j) {
    o[j]     = f2bf(a[j] * wa[j] * rn);
    o[4 + j] = f2bf(b[j] * wb[j] * rn);
  }
  *(s16x8*)(out + row * 2048 + base) = o;
}

// ---------------- GEMM: C[M,N] = A[M,K](bf16) * B[N,K]^T(bf16) --------------
template <int MODE>
__global__ __launch_bounds__(256, 2) void gemm_bt_kernel(
    const short* __restrict__ A, const short* __restrict__ B,
    void* __restrict__ Cv, const float* __restrict__ resid,
    int M, int N, int K)
{
  __shared__ short As[128 * 32];
  __shared__ short Bs[128 * 32];
  int tid = threadIdx.x;
  int lane = tid & 63;
  int w = tid >> 6;
  int r = lane & 15, g = lane >> 4;
  int wr = w >> 1, wc = w & 1;
  size_t row0 = (size_t)blockIdx.y * 128;
  size_t col0 = (size_t)blockIdx.x * 128;

  f32x4 acc[4][4];
  #pragma unroll
  for (int i = 0; i < 4; ++i)
    #pragma unroll
    for (int j = 0; j < 4; ++j) acc[i][j] = (f32x4){0.f, 0.f, 0.f, 0.f};

  const short* Ablk = A + row0 * K;
  const short* Bblk = B + col0 * K;
  int arow = tid >> 2;
  int akk = (tid & 3) << 3;

  for (int k0 = 0; k0 < K; k0 += 32) {
    #pragma unroll
    for (int i = 0; i < 2; ++i) {
      int chunk = i * 256 + tid;
      int rr = i * 64 + arow;
      __builtin_amdgcn_global_load_lds(
          (const __attribute__((address_space(1))) unsigned int*)(Ablk + (size_t)rr * K + k0 + akk),
          (__attribute__((address_space(3))) unsigned int*)(&As[chunk * 8]), 16, 0, 0);
      __builtin_amdgcn_global_load_lds(
          (const __attribute__((address_space(1))) unsigned int*)(Bblk + (size_t)rr * K + k0 + akk),
          (__attribute__((address_space(3))) unsigned int*)(&Bs[chunk * 8]), 16, 0, 0);
    }
    __syncthreads();
    s16x8 af[4], bfr[4];
    #pragma unroll
    for (int mm = 0; mm < 4; ++mm)
      af[mm] = *(const s16x8*)(&As[(wr * 64 + mm * 16 + r) * 32 + g * 8]);
    #pragma unroll
    for (int nn = 0; nn < 4; ++nn)
      bfr[nn] = *(const s16x8*)(&Bs[(wc * 64 + nn * 16 + r) * 32 + g * 8]);
    #pragma unroll
    for (int mm = 0; mm < 4; ++mm)
      #pragma unroll
      for (int nn = 0; nn < 4; ++nn)
        acc[mm][nn] = MFMA_BF16(af[mm], bfr[nn], acc[mm][nn], 0, 0, 0);
    __syncthreads();
  }

  #pragma unroll
  for (int mm = 0; mm < 4; ++mm) {
    #pragma unroll
    for (int nn = 0; nn < 4; ++nn) {
      #pragma unroll
      for (int j = 0; j < 4; ++j) {
        size_t rr = row0 + wr * 64 + mm * 16 + g * 4 + j;
        size_t cc = col0 + wc * 64 + nn * 16 + r;
        size_t idx = rr * (size_t)N + cc;
        if constexpr (MODE == 0) {
          ((short*)Cv)[idx] = f2bf(acc[mm][nn][j]);
        } else if constexpr (MODE == 1) {
          ((float*)Cv)[idx] = acc[mm][nn][j] + resid[idx];
        } else {
          short* gp = (short*)Cv;
          float gv = bf2f(gp[idx]);
          float sg = gv / (1.0f + __expf(-gv));
          gp[idx] = f2bf(sg * acc[mm][nn][j]);
        }
      }
    }
  }
}

// ---------------- V transpose: kv[B*S,256] cols 128..255 -> [B][128][S] -----
__global__ __launch_bounds__(256) void transpose_v_kernel(
    const short* __restrict__ kv, short* __restrict__ vt)
{
  __shared__ short t[64][65];
  int b = blockIdx.z;
  int s0 = blockIdx.x * 64;
  int d0 = blockIdx.y * 64;
  int tid = threadIdx.x;
  #pragma unroll
  for (int i = 0; i < 16; ++i) {
    int e = i * 256 + tid;
    int sr = e >> 6, dc = e & 63;
    t[sr][dc] = kv[(size_t)(b * 2048 + s0 + sr) * 256 + 128 + d0 + dc];
  }
  __syncthreads();
  #pragma unroll
  for (int i = 0; i < 16; ++i) {
    int e = i * 256 + tid;
    int dr = e >> 6, sc = e & 63;
    vt[(size_t)b * 128 * 2048 + (size_t)(d0 + dr) * 2048 + s0 + sc] = t[sc][dr];
  }
}

// ---------------- Flash attention (MQA), wave-split KV, DPP softmax ---------
// Block: 4 waves over same 16 q-rows; wave w covers kv [w*512,(w+1)*512).
// Scores come pre-scaled (1/sqrt(hd) folded into wq). Lane-local l (no per-iter
// sum tree); DPP max tree; defer-rescale THR=8; chunked cross-wave combine.
__global__ __launch_bounds__(256) void attn_kernel(
    const short* __restrict__ q, const short* __restrict__ kv,
    const short* __restrict__ vt, short* __restrict__ out)
{
  const int S = 2048;
  int tid = threadIdx.x;
  int w = tid >> 6;
  int lane = tid & 63;
  int r = lane & 15, g = lane >> 4;
  int h = blockIdx.y, b = blockIdx.z;
  int qrow0 = blockIdx.x * 16;

  __shared__ char UBUF[8192];           // P short[4][16][40] | LoF float[4][16][32]
  __shared__ float Lm[4][16], Ll[4][16], Smg[16], Sil[16];
  short* Pw = ((short*)UBUF) + w * 640; // per-wave [16][40]
  float* LoF = (float*)UBUF;            // [4][16][32] (epilogue)

  const short* qbase = q + ((size_t)(b * S + qrow0 + r)) * 2048 + h * 128;
  s16x8 qa[4];
  #pragma unroll
  for (int dc = 0; dc < 4; ++dc) qa[dc] = *(const s16x8*)(qbase + dc * 32 + g * 8);

  f32x4 o[8];
  #pragma unroll
  for (int dt = 0; dt < 8; ++dt) o[dt] = (f32x4){0.f, 0.f, 0.f, 0.f};
  float m[4], l[4];
  #pragma unroll
  for (int j = 0; j < 4; ++j) { m[j] = -1e30f; l[j] = 0.f; }

  const short* kbase = kv + (size_t)b * S * 256;
  const short* vbase = vt + (size_t)b * 128 * S;
  int kv0 = w * 512;

  s16x8 kc[8];
  #pragma unroll
  for (int dc = 0; dc < 4; ++dc) {
    kc[dc]     = *(const s16x8*)(kbase + (size_t)(kv0 + r) * 256 + dc * 32 + g * 8);
    kc[4 + dc] = *(const s16x8*)(kbase + (size_t)(kv0 + 16 + r) * 256 + dc * 32 + g * 8);
  }

  for (int it = 0; it < 16; ++it) {
    int kvc = kv0 + it * 32;
    // V loads early: consumed only after softmax
    s16x8 vb[8];
    #pragma unroll
    for (int dt = 0; dt < 8; ++dt)
      vb[dt] = *(const s16x8*)(vbase + (size_t)(dt * 16 + r) * S + kvc + g * 8);
    f32x4 s0 = {0.f, 0.f, 0.f, 0.f}, s1 = {0.f, 0.f, 0.f, 0.f};
    __builtin_amdgcn_s_setprio(1);
    #pragma unroll
    for (int dc = 0; dc < 4; ++dc) {
      s0 = MFMA_BF16(qa[dc], kc[dc], s0, 0, 0, 0);
      s1 = MFMA_BF16(qa[dc], kc[4 + dc], s1, 0, 0, 0);
    }
    __builtin_amdgcn_s_setprio(0);
    if (it < 15) {
      int kvn = kvc + 32;
      #pragma unroll
      for (int dc = 0; dc < 4; ++dc) {
        kc[dc]     = *(const s16x8*)(kbase + (size_t)(kvn + r) * 256 + dc * 32 + g * 8);
        kc[4 + dc] = *(const s16x8*)(kbase + (size_t)(kvn + 16 + r) * 256 + dc * 32 + g * 8);
      }
    }
    float mx[4];
    #pragma unroll
    for (int j = 0; j < 4; ++j) mx[j] = rowmax16(fmaxf(s0[j], s1[j]));
    // defer-rescale: only pay alpha/exp/o-scale when the running max grows >8
    bool nd = (mx[0] > m[0] + 8.f) | (mx[1] > m[1] + 8.f)
            | (mx[2] > m[2] + 8.f) | (mx[3] > m[3] + 8.f);
    if (__any(nd)) {
      float alpha[4];
      #pragma unroll
      for (int j = 0; j < 4; ++j) {
        float mn = fmaxf(m[j], mx[j]);
        alpha[j] = __expf(m[j] - mn);
        m[j] = mn;
        l[j] *= alpha[j];
      }
      #pragma unroll
      for (int dt = 0; dt < 8; ++dt)
        #pragma unroll
        for (int j = 0; j < 4; ++j) o[dt][j] *= alpha[j];
    }
    float p0[4], p1[4];
    #pragma unroll
    for (int j = 0; j < 4; ++j) {
      p0[j] = __expf(s0[j] - m[j]);
      p1[j] = __expf(s1[j] - m[j]);
      l[j] += p0[j] + p1[j];       // lane-local partial denominator
    }
    #pragma unroll
    for (int j = 0; j < 4; ++j) {
      Pw[(g * 4 + j) * 40 + r]      = f2bf(p0[j]);
      Pw[(g * 4 + j) * 40 + 16 + r] = f2bf(p1[j]);
    }
    asm volatile("s_waitcnt lgkmcnt(0)" ::: "memory");
    __builtin_amdgcn_sched_barrier(0);
    s16x8 pa = *(const s16x8*)(Pw + r * 40 + g * 8);
    __builtin_amdgcn_s_setprio(1);
    #pragma unroll
    for (int dt = 0; dt < 8; ++dt)
      o[dt] = MFMA_BF16(pa, vb[dt], o[dt], 0, 0, 0);
    __builtin_amdgcn_s_setprio(0);
  }

  // ---- cross-wave combine ----
  #pragma unroll
  for (int j = 0; j < 4; ++j) l[j] = rowsum16(l[j]);
  if (r == 0) {
    #pragma unroll
    for (int j = 0; j < 4; ++j) { Lm[w][g * 4 + j] = m[j]; Ll[w][g * 4 + j] = l[j]; }
  }
  __syncthreads();
  if (tid < 16) {
    int row = tid;
    float mg = fmaxf(fmaxf(Lm[0][row], Lm[1][row]), fmaxf(Lm[2][row], Lm[3][row]));
    float lg = Ll[0][row] * __expf(Lm[0][row] - mg)
             + Ll[1][row] * __expf(Lm[1][row] - mg)
             + Ll[2][row] * __expf(Lm[2][row] - mg)
             + Ll[3][row] * __expf(Lm[3][row] - mg);
    Smg[row] = mg;
    Sil[row] = 1.0f / lg;
  }
  __syncthreads();
  float scl[4];
  #pragma unroll
  for (int j = 0; j < 4; ++j) scl[j] = __expf(m[j] - Smg[g * 4 + j]);
  int orow = tid >> 4, ocp = (tid & 15) * 2;
  #pragma unroll
  for (int c = 0; c < 4; ++c) {
    #pragma unroll
    for (int t = 0; t < 2; ++t) {
      int dt = c * 2 + t;
      #pragma unroll
      for (int j = 0; j < 4; ++j)
        LoF[(w * 16 + g * 4 + j) * 32 + t * 16 + r] = o[dt][j] * scl[j];
    }
    __syncthreads();
    float a0 = LoF[orow * 32 + ocp]      + LoF[(16 + orow) * 32 + ocp]
             + LoF[(32 + orow) * 32 + ocp] + LoF[(48 + orow) * 32 + ocp];
    float a1 = LoF[orow * 32 + ocp + 1]      + LoF[(16 + orow) * 32 + ocp + 1]
             + LoF[(32 + orow) * 32 + ocp + 1] + LoF[(48 + orow) * 32 + ocp + 1];
    float inv = Sil[orow];
    s16x2 ov;
    ov[0] = f2bf(a0 * inv);
    ov[1] = f2bf(a1 * inv);
    *(s16x2*)(out + (size_t)(b * S + qrow0 + orow) * 2048 + h * 128 + c * 32 + ocp) = ov;
    __syncthreads();
  }
}

extern "C" void kernel_launch(void* const* d_in, const int* in_sizes, int n_in,
                              void* d_out, int out_size, void* d_ws, size_t ws_size,
                              hipStream_t stream) {
  const float* x   = (const float*)d_in[0];
  const float* n1w = (const float*)d_in[1];
  const float* wq  = (const float*)d_in[2];
  const float* wk  = (const float*)d_in[3];
  const float* wv  = (const float*)d_in[4];
  const float* wo  = (const float*)d_in[5];
  const float* n2w = (const float*)d_in[6];
  const float* w1  = (const float*)d_in[7];
  const float* w2  = (const float*)d_in[8];
  const float* w3  = (const float*)d_in[9];
  float* out = (float*)d_out;   // doubles as fp32 xmid buffer
  char* ws = (char*)d_ws;
  const size_t MB = 1ull << 20;
  short* wqb  = (short*)(ws);              //  8 MB (pre-scaled by 1/sqrt(128))
  short* wob  = (short*)(ws + 8 * MB);     //  8 MB
  short* w1b  = (short*)(ws + 16 * MB);    // 32 MB
  short* w2b  = (short*)(ws + 48 * MB);    // 32 MB
  short* w3b  = (short*)(ws + 80 * MB);    // 32 MB
  short* wkvb = (short*)(ws + 112 * MB);   //  1 MB [256,2048]
  short* h1   = (short*)(ws + 113 * MB);   // 16 MB
  short* gbuf = (short*)(ws + 129 * MB);   // 64 MB; overlays qb/kvb/vtb
  short* qb   = (short*)(ws + 129 * MB);   // 16 MB
  short* kvb  = (short*)(ws + 145 * MB);   //  2 MB
  short* vtb  = (short*)(ws + 147 * MB);   //  1 MB

  const float qscale = 0.08838834764831845f;  // 1/sqrt(128) folded into wq
  cvt_kernel<<<2048, 256, 0, stream>>>(wq, wqb, 4194304, qscale);
  cvt_kernel<<<128,  256, 0, stream>>>(wk, wkvb, 262144, 1.0f);
  cvt_kernel<<<128,  256, 0, stream>>>(wv, wkvb + 262144, 262144, 1.0f);
  cvt_kernel<<<2048, 256, 0, stream>>>(wo, wob, 4194304, 1.0f);
  cvt_kernel<<<8192, 256, 0, stream>>>(w1, w1b, 16777216, 1.0f);
  cvt_kernel<<<8192, 256, 0, stream>>>(w2, w2b, 16777216, 1.0f);
  cvt_kernel<<<8192, 256, 0, stream>>>(w3, w3b, 16777216, 1.0f);

  rmsnorm_kernel<<<4096, 256, 0, stream>>>(x, n1w, h1);
  gemm_bt_kernel<0><<<dim3(16, 32), 256, 0, stream>>>(h1, wqb, qb, nullptr, 4096, 2048, 2048);
  gemm_bt_kernel<0><<<dim3(2, 32), 256, 0, stream>>>(h1, wkvb, kvb, nullptr, 4096, 256, 2048);
  transpose_v_kernel<<<dim3(32, 2, 2), 256, 0, stream>>>(kvb, vtb);
  attn_kernel<<<dim3(128, 16, 2), 256, 0, stream>>>(qb, kvb, vtb, h1);
  gemm_bt_kernel<1><<<dim3(16, 32), 256, 0, stream>>>(h1, wob, out, x, 4096, 2048, 2048);
  rmsnorm_kernel<<<4096, 256, 0, stream>>>(out, n2w, h1);
  gemm_bt_kernel<0><<<dim3(64, 32), 256, 0, stream>>>(h1, w1b, gbuf, nullptr, 4096, 8192, 2048);
  gemm_bt_kernel<2><<<dim3(64, 32), 256, 0, stream>>>(h1, w3b, gbuf, nullptr, 4096, 8192, 2048);
  gemm_bt_kernel<1><<<dim3(16, 32), 256, 0, stream>>>(gbuf, w2b, out, out, 4096, 2048, 8192);
}

// Round 4
// 921.922 us; speedup vs baseline: 1.6252x; 1.3429x over previous
//
#include <hip/hip_runtime.h>
#include <hip/hip_bf16.h>

typedef __attribute__((ext_vector_type(4))) float f32x4;
typedef __attribute__((ext_vector_type(8))) short s16x8;
typedef __attribute__((ext_vector_type(4))) short s16x4;
typedef __attribute__((ext_vector_type(2))) short s16x2;

#define MFMA_BF16 __builtin_amdgcn_mfma_f32_16x16x32_bf16

__device__ inline short f2bf(float f) {
  unsigned u = __float_as_uint(f);
  u = (u + 0x7FFFu + ((u >> 16) & 1u)) >> 16;
  return (short)u;
}
__device__ inline float bf2f(short s) {
  return __uint_as_float(((unsigned)(unsigned short)s) << 16);
}

#define DPPF(x, ctrl) __int_as_float(__builtin_amdgcn_update_dpp( \
    __float_as_int(x), __float_as_int(x), ctrl, 0xF, 0xF, false))
__device__ inline float rowmax16(float x) {
  x = fmaxf(x, DPPF(x, 0xB1));
  x = fmaxf(x, DPPF(x, 0x4E));
  x = fmaxf(x, DPPF(x, 0x124));
  x = fmaxf(x, DPPF(x, 0x128));
  return x;
}
__device__ inline float rowsum16(float x) {
  x += DPPF(x, 0xB1);
  x += DPPF(x, 0x4E);
  x += DPPF(x, 0x124);
  x += DPPF(x, 0x128);
  return x;
}

// ---------------- fp32 -> bf16 conversion (optional uniform scale) ----------
__global__ __launch_bounds__(256) void cvt_kernel(
    const float* __restrict__ in, short* __restrict__ out, int n, float scale)
{
  int idx = (blockIdx.x * 256 + threadIdx.x) * 8;
  if (idx >= n) return;
  f32x4 a = *(const f32x4*)(in + idx);
  f32x4 b = *(const f32x4*)(in + idx + 4);
  s16x8 o;
  #pragma unroll
  for (int j = 0; j < 4; ++j) { o[j] = f2bf(a[j] * scale); o[4 + j] = f2bf(b[j] * scale); }
  *(s16x8*)(out + idx) = o;
}

// ---------------- RMSNorm: fp32 in -> bf16 out, one row (2048) per block ----
__global__ __launch_bounds__(256) void rmsnorm_kernel(
    const float* __restrict__ x, const float* __restrict__ w, short* __restrict__ out)
{
  size_t row = blockIdx.x;
  const float* xr = x + row * 2048;
  int base = threadIdx.x * 8;
  f32x4 a = *(const f32x4*)(xr + base);
  f32x4 b = *(const f32x4*)(xr + base + 4);
  float ss = a[0]*a[0] + a[1]*a[1] + a[2]*a[2] + a[3]*a[3]
           + b[0]*b[0] + b[1]*b[1] + b[2]*b[2] + b[3]*b[3];
  #pragma unroll
  for (int off = 1; off < 64; off <<= 1) ss += __shfl_xor(ss, off, 64);
  __shared__ float red[4];
  if ((threadIdx.x & 63) == 0) red[threadIdx.x >> 6] = ss;
  __syncthreads();
  float tot = red[0] + red[1] + red[2] + red[3];
  float rn = rsqrtf(tot * (1.0f / 2048.0f) + 1e-6f) * 0.022097086912079608f;
  f32x4 wa = *(const f32x4*)(w + base);
  f32x4 wb = *(const f32x4*)(w + base + 4);
  s16x8 o;
  #pragma unroll
  for (int j = 0; j < 4; ++j) {
    o[j]     = f2bf(a[j] * wa[j] * rn);
    o[4 + j] = f2bf(b[j] * wb[j] * rn);
  }
  *(s16x8*)(out + row * 2048 + base) = o;
}

// ---------------- GEMM: C[M,N] = A[M,K](bf16) * B[N,K]^T(bf16) --------------
template <int MODE>
__global__ __launch_bounds__(256, 2) void gemm_bt_kernel(
    const short* __restrict__ A, const short* __restrict__ B,
    void* __restrict__ Cv, const float* __restrict__ resid,
    int M, int N, int K)
{
  __shared__ short As[128 * 32];
  __shared__ short Bs[128 * 32];
  int tid = threadIdx.x;
  int lane = tid & 63;
  int w = tid >> 6;
  int r = lane & 15, g = lane >> 4;
  int wr = w >> 1, wc = w & 1;
  size_t row0 = (size_t)blockIdx.y * 128;
  size_t col0 = (size_t)blockIdx.x * 128;

  f32x4 acc[4][4];
  #pragma unroll
  for (int i = 0; i < 4; ++i)
    #pragma unroll
    for (int j = 0; j < 4; ++j) acc[i][j] = (f32x4){0.f, 0.f, 0.f, 0.f};

  const short* Ablk = A + row0 * K;
  const short* Bblk = B + col0 * K;
  int arow = tid >> 2;
  int akk = (tid & 3) << 3;

  for (int k0 = 0; k0 < K; k0 += 32) {
    #pragma unroll
    for (int i = 0; i < 2; ++i) {
      int chunk = i * 256 + tid;
      int rr = i * 64 + arow;
      __builtin_amdgcn_global_load_lds(
          (const __attribute__((address_space(1))) unsigned int*)(Ablk + (size_t)rr * K + k0 + akk),
          (__attribute__((address_space(3))) unsigned int*)(&As[chunk * 8]), 16, 0, 0);
      __builtin_amdgcn_global_load_lds(
          (const __attribute__((address_space(1))) unsigned int*)(Bblk + (size_t)rr * K + k0 + akk),
          (__attribute__((address_space(3))) unsigned int*)(&Bs[chunk * 8]), 16, 0, 0);
    }
    __syncthreads();
    s16x8 af[4], bfr[4];
    #pragma unroll
    for (int mm = 0; mm < 4; ++mm)
      af[mm] = *(const s16x8*)(&As[(wr * 64 + mm * 16 + r) * 32 + g * 8]);
    #pragma unroll
    for (int nn = 0; nn < 4; ++nn)
      bfr[nn] = *(const s16x8*)(&Bs[(wc * 64 + nn * 16 + r) * 32 + g * 8]);
    #pragma unroll
    for (int mm = 0; mm < 4; ++mm)
      #pragma unroll
      for (int nn = 0; nn < 4; ++nn)
        acc[mm][nn] = MFMA_BF16(af[mm], bfr[nn], acc[mm][nn], 0, 0, 0);
    __syncthreads();
  }

  #pragma unroll
  for (int mm = 0; mm < 4; ++mm) {
    #pragma unroll
    for (int nn = 0; nn < 4; ++nn) {
      #pragma unroll
      for (int j = 0; j < 4; ++j) {
        size_t rr = row0 + wr * 64 + mm * 16 + g * 4 + j;
        size_t cc = col0 + wc * 64 + nn * 16 + r;
        size_t idx = rr * (size_t)N + cc;
        if constexpr (MODE == 0) {
          ((short*)Cv)[idx] = f2bf(acc[mm][nn][j]);
        } else if constexpr (MODE == 1) {
          ((float*)Cv)[idx] = acc[mm][nn][j] + resid[idx];
        } else {
          short* gp = (short*)Cv;
          float gv = bf2f(gp[idx]);
          float sg = gv / (1.0f + __expf(-gv));
          gp[idx] = f2bf(sg * acc[mm][nn][j]);
        }
      }
    }
  }
}

// ---------------- V transpose: kv[B*S,256] cols 128..255 -> [B][128][S] -----
__global__ __launch_bounds__(256) void transpose_v_kernel(
    const short* __restrict__ kv, short* __restrict__ vt)
{
  __shared__ short t[64][65];
  int b = blockIdx.z;
  int s0 = blockIdx.x * 64;
  int d0 = blockIdx.y * 64;
  int tid = threadIdx.x;
  #pragma unroll
  for (int i = 0; i < 16; ++i) {
    int e = i * 256 + tid;
    int sr = e >> 6, dc = e & 63;
    t[sr][dc] = kv[(size_t)(b * 2048 + s0 + sr) * 256 + 128 + d0 + dc];
  }
  __syncthreads();
  #pragma unroll
  for (int i = 0; i < 16; ++i) {
    int e = i * 256 + tid;
    int dr = e >> 6, sc = e & 63;
    vt[(size_t)b * 128 * 2048 + (size_t)(d0 + dr) * 2048 + s0 + sc] = t[sc][dr];
  }
}

// ---------------- Flash attention (MQA), LDS-staged K/V, 4 waves x 32 q-rows
// Block covers 128 q-rows of one (b,h). K tile [32][128] and Vt tile [128][32]
// staged in double-buffered LDS via global_load_lds with pre-swizzled source
// (XOR on 16B-chunk index; K: row&7, V: row&3). All 4 waves share the tiles.
__global__ __launch_bounds__(256, 2) void attn_kernel(
    const short* __restrict__ q, const short* __restrict__ kv,
    const short* __restrict__ vt, short* __restrict__ out)
{
  const int S = 2048;
  int tid = threadIdx.x;
  int w = tid >> 6;
  int lane = tid & 63;
  int r = lane & 15, g = lane >> 4;
  int h = blockIdx.y, b = blockIdx.z;
  int qrow0 = blockIdx.x * 128 + w * 32;

  __shared__ short Ks[2][4096];      // [32 kv][128 d], swizzled chunks
  __shared__ short Vs[2][4096];      // [128 d][32 kv], swizzled chunks
  __shared__ short Ps[4][32][40];    // per-wave P, padded

  const short* kvsrc = kv + (size_t)b * S * 256;        // K in cols 0..127
  const short* vsrc  = vt + (size_t)b * 128 * S;

  // Q fragments: 2 groups of 16 rows
  const short* qbase = q + ((size_t)(b * S + qrow0 + r)) * 2048 + h * 128;
  s16x8 qa[2][4];
  #pragma unroll
  for (int gq = 0; gq < 2; ++gq)
    #pragma unroll
    for (int dc = 0; dc < 4; ++dc)
      qa[gq][dc] = *(const s16x8*)(qbase + gq * 16 * 2048 + dc * 32 + g * 8);

  f32x4 o[2][8];
  #pragma unroll
  for (int gq = 0; gq < 2; ++gq)
    #pragma unroll
    for (int dt = 0; dt < 8; ++dt) o[gq][dt] = (f32x4){0.f, 0.f, 0.f, 0.f};
  float m[2][4], l[2][4];
  #pragma unroll
  for (int gq = 0; gq < 2; ++gq)
    #pragma unroll
    for (int j = 0; j < 4; ++j) { m[gq][j] = -1e30f; l[gq][j] = 0.f; }

#define STAGE(KVT, BSEL)                                                        \
  {                                                                             \
    int kv0s = (KVT) * 32;                                                      \
    _Pragma("unroll")                                                           \
    for (int i = 0; i < 2; ++i) {                                               \
      int c = w * 64 + lane + i * 256;                                          \
      int krow = c >> 4, kcp = c & 15;                                          \
      __builtin_amdgcn_global_load_lds(                                         \
          (const __attribute__((address_space(1))) unsigned int*)               \
              (kvsrc + (size_t)(kv0s + krow) * 256 + ((kcp ^ (krow & 7)) << 3)),\
          (__attribute__((address_space(3))) unsigned int*)(&Ks[BSEL][c * 8]),  \
          16, 0, 0);                                                            \
      int vrow = c >> 2, vcp = c & 3;                                           \
      __builtin_amdgcn_global_load_lds(                                         \
          (const __attribute__((address_space(1))) unsigned int*)               \
              (vsrc + (size_t)vrow * S + kv0s + ((vcp ^ (vrow & 3)) << 3)),     \
          (__attribute__((address_space(3))) unsigned int*)(&Vs[BSEL][c * 8]),  \
          16, 0, 0);                                                            \
    }                                                                           \
  }

  STAGE(0, 0);
  __syncthreads();

  for (int it = 0; it < 64; ++it) {
    int cur = it & 1;
    if (it < 63) STAGE(it + 1, cur ^ 1);

    // K fragments from swizzled LDS (shared by both q-groups)
    s16x8 kc0[4], kc1[4], vb[8];
    #pragma unroll
    for (int dc = 0; dc < 4; ++dc) {
      kc0[dc] = *(const s16x8*)(&Ks[cur][r * 128 + (((dc * 4 + g) ^ (r & 7)) << 3)]);
      kc1[dc] = *(const s16x8*)(&Ks[cur][(16 + r) * 128 + (((dc * 4 + g) ^ (r & 7)) << 3)]);
    }
    #pragma unroll
    for (int dt = 0; dt < 8; ++dt)
      vb[dt] = *(const s16x8*)(&Vs[cur][(dt * 16 + r) * 32 + ((g ^ (r & 3)) << 3)]);

    f32x4 sc0[2], sc1[2];
    #pragma unroll
    for (int gq = 0; gq < 2; ++gq) { sc0[gq] = (f32x4){0.f,0.f,0.f,0.f}; sc1[gq] = (f32x4){0.f,0.f,0.f,0.f}; }
    __builtin_amdgcn_s_setprio(1);
    #pragma unroll
    for (int dc = 0; dc < 4; ++dc) {
      #pragma unroll
      for (int gq = 0; gq < 2; ++gq) {
        sc0[gq] = MFMA_BF16(qa[gq][dc], kc0[dc], sc0[gq], 0, 0, 0);
        sc1[gq] = MFMA_BF16(qa[gq][dc], kc1[dc], sc1[gq], 0, 0, 0);
      }
    }
    __builtin_amdgcn_s_setprio(0);

    float p0[2][4], p1[2][4];
    #pragma unroll
    for (int gq = 0; gq < 2; ++gq) {
      float mx[4];
      #pragma unroll
      for (int j = 0; j < 4; ++j) mx[j] = rowmax16(fmaxf(sc0[gq][j], sc1[gq][j]));
      bool nd = (mx[0] > m[gq][0] + 8.f) | (mx[1] > m[gq][1] + 8.f)
              | (mx[2] > m[gq][2] + 8.f) | (mx[3] > m[gq][3] + 8.f);
      if (__any(nd)) {
        #pragma unroll
        for (int j = 0; j < 4; ++j) {
          float mn = fmaxf(m[gq][j], mx[j]);
          float alpha = __expf(m[gq][j] - mn);
          m[gq][j] = mn;
          l[gq][j] *= alpha;
          #pragma unroll
          for (int dt = 0; dt < 8; ++dt) o[gq][dt][j] *= alpha;
        }
      }
      #pragma unroll
      for (int j = 0; j < 4; ++j) {
        p0[gq][j] = __expf(sc0[gq][j] - m[gq][j]);
        p1[gq][j] = __expf(sc1[gq][j] - m[gq][j]);
        l[gq][j] += p0[gq][j] + p1[gq][j];
      }
      #pragma unroll
      for (int j = 0; j < 4; ++j) {
        Ps[w][gq * 16 + g * 4 + j][r]      = f2bf(p0[gq][j]);
        Ps[w][gq * 16 + g * 4 + j][16 + r] = f2bf(p1[gq][j]);
      }
    }
    asm volatile("s_waitcnt lgkmcnt(0)" ::: "memory");
    __builtin_amdgcn_sched_barrier(0);
    s16x8 pa0 = *(const s16x8*)(&Ps[w][r][g * 8]);
    s16x8 pa1 = *(const s16x8*)(&Ps[w][16 + r][g * 8]);
    __builtin_amdgcn_s_setprio(1);
    #pragma unroll
    for (int dt = 0; dt < 8; ++dt) {
      o[0][dt] = MFMA_BF16(pa0, vb[dt], o[0][dt], 0, 0, 0);
      o[1][dt] = MFMA_BF16(pa1, vb[dt], o[1][dt], 0, 0, 0);
    }
    __builtin_amdgcn_s_setprio(0);
    __syncthreads();
  }

  // epilogue: per group, reduce l over the 16-lane row and write
  #pragma unroll
  for (int gq = 0; gq < 2; ++gq) {
    float linv[4];
    #pragma unroll
    for (int j = 0; j < 4; ++j) linv[j] = 1.0f / rowsum16(l[gq][j]);
    short* ob = out + ((size_t)(b * S + qrow0 + gq * 16)) * 2048 + h * 128;
    #pragma unroll
    for (int dt = 0; dt < 8; ++dt)
      #pragma unroll
      for (int j = 0; j < 4; ++j)
        ob[(size_t)(g * 4 + j) * 2048 + dt * 16 + r] = f2bf(o[gq][dt][j] * linv[j]);
  }
#undef STAGE
}

extern "C" void kernel_launch(void* const* d_in, const int* in_sizes, int n_in,
                              void* d_out, int out_size, void* d_ws, size_t ws_size,
                              hipStream_t stream) {
  const float* x   = (const float*)d_in[0];
  const float* n1w = (const float*)d_in[1];
  const float* wq  = (const float*)d_in[2];
  const float* wk  = (const float*)d_in[3];
  const float* wv  = (const float*)d_in[4];
  const float* wo  = (const float*)d_in[5];
  const float* n2w = (const float*)d_in[6];
  const float* w1  = (const float*)d_in[7];
  const float* w2  = (const float*)d_in[8];
  const float* w3  = (const float*)d_in[9];
  float* out = (float*)d_out;   // doubles as fp32 xmid buffer
  char* ws = (char*)d_ws;
  const size_t MB = 1ull << 20;
  short* wqb  = (short*)(ws);              //  8 MB (pre-scaled by 1/sqrt(128))
  short* wob  = (short*)(ws + 8 * MB);     //  8 MB
  short* w1b  = (short*)(ws + 16 * MB);    // 32 MB
  short* w2b  = (short*)(ws + 48 * MB);    // 32 MB
  short* w3b  = (short*)(ws + 80 * MB);    // 32 MB
  short* wkvb = (short*)(ws + 112 * MB);   //  1 MB [256,2048]
  short* h1   = (short*)(ws + 113 * MB);   // 16 MB
  short* gbuf = (short*)(ws + 129 * MB);   // 64 MB; overlays qb/kvb/vtb
  short* qb   = (short*)(ws + 129 * MB);   // 16 MB
  short* kvb  = (short*)(ws + 145 * MB);   //  2 MB
  short* vtb  = (short*)(ws + 147 * MB);   //  1 MB

  const float qscale = 0.08838834764831845f;  // 1/sqrt(128) folded into wq
  cvt_kernel<<<2048, 256, 0, stream>>>(wq, wqb, 4194304, qscale);
  cvt_kernel<<<128,  256, 0, stream>>>(wk, wkvb, 262144, 1.0f);
  cvt_kernel<<<128,  256, 0, stream>>>(wv, wkvb + 262144, 262144, 1.0f);
  cvt_kernel<<<2048, 256, 0, stream>>>(wo, wob, 4194304, 1.0f);
  cvt_kernel<<<8192, 256, 0, stream>>>(w1, w1b, 16777216, 1.0f);
  cvt_kernel<<<8192, 256, 0, stream>>>(w2, w2b, 16777216, 1.0f);
  cvt_kernel<<<8192, 256, 0, stream>>>(w3, w3b, 16777216, 1.0f);

  rmsnorm_kernel<<<4096, 256, 0, stream>>>(x, n1w, h1);
  gemm_bt_kernel<0><<<dim3(16, 32), 256, 0, stream>>>(h1, wqb, qb, nullptr, 4096, 2048, 2048);
  gemm_bt_kernel<0><<<dim3(2, 32), 256, 0, stream>>>(h1, wkvb, kvb, nullptr, 4096, 256, 2048);
  transpose_v_kernel<<<dim3(32, 2, 2), 256, 0, stream>>>(kvb, vtb);
  attn_kernel<<<dim3(16, 16, 2), 256, 0, stream>>>(qb, kvb, vtb, h1);
  gemm_bt_kernel<1><<<dim3(16, 32), 256, 0, stream>>>(h1, wob, out, x, 4096, 2048, 2048);
  rmsnorm_kernel<<<4096, 256, 0, stream>>>(out, n2w, h1);
  gemm_bt_kernel<0><<<dim3(64, 32), 256, 0, stream>>>(h1, w1b, gbuf, nullptr, 4096, 8192, 2048);
  gemm_bt_kernel<2><<<dim3(64, 32), 256, 0, stream>>>(h1, w3b, gbuf, nullptr, 4096, 8192, 2048);
  gemm_bt_kernel<1><<<dim3(16, 32), 256, 0, stream>>>(gbuf, w2b, out, out, 4096, 2048, 8192);
}

// Round 6
// 897.598 us; speedup vs baseline: 1.6692x; 1.0271x over previous
//
#include <hip/hip_runtime.h>
#include <hip/hip_bf16.h>

typedef __attribute__((ext_vector_type(4))) float f32x4;
typedef __attribute__((ext_vector_type(8))) short s16x8;
typedef __attribute__((ext_vector_type(4))) short s16x4;
typedef __attribute__((ext_vector_type(2))) short s16x2;

#define MFMA_BF16 __builtin_amdgcn_mfma_f32_16x16x32_bf16

__device__ inline short f2bf(float f) {
  unsigned u = __float_as_uint(f);
  u = (u + 0x7FFFu + ((u >> 16) & 1u)) >> 16;
  return (short)u;
}
__device__ inline float bf2f(short s) {
  return __uint_as_float(((unsigned)(unsigned short)s) << 16);
}

#define DPPF(x, ctrl) __int_as_float(__builtin_amdgcn_update_dpp( \
    __float_as_int(x), __float_as_int(x), ctrl, 0xF, 0xF, false))
__device__ inline float rowmax16(float x) {
  x = fmaxf(x, DPPF(x, 0xB1));
  x = fmaxf(x, DPPF(x, 0x4E));
  x = fmaxf(x, DPPF(x, 0x124));
  x = fmaxf(x, DPPF(x, 0x128));
  return x;
}
__device__ inline float rowsum16(float x) {
  x += DPPF(x, 0xB1);
  x += DPPF(x, 0x4E);
  x += DPPF(x, 0x124);
  x += DPPF(x, 0x128);
  return x;
}

// ---------------- fp32 -> bf16 conversion (optional uniform scale) ----------
__global__ __launch_bounds__(256) void cvt_kernel(
    const float* __restrict__ in, short* __restrict__ out, int n, float scale)
{
  int idx = (blockIdx.x * 256 + threadIdx.x) * 8;
  if (idx >= n) return;
  f32x4 a = *(const f32x4*)(in + idx);
  f32x4 b = *(const f32x4*)(in + idx + 4);
  s16x8 o;
  #pragma unroll
  for (int j = 0; j < 4; ++j) { o[j] = f2bf(a[j] * scale); o[4 + j] = f2bf(b[j] * scale); }
  *(s16x8*)(out + idx) = o;
}

// ---------------- RMSNorm: fp32 in -> bf16 out, one row (2048) per block ----
__global__ __launch_bounds__(256) void rmsnorm_kernel(
    const float* __restrict__ x, const float* __restrict__ w, short* __restrict__ out)
{
  size_t row = blockIdx.x;
  const float* xr = x + row * 2048;
  int base = threadIdx.x * 8;
  f32x4 a = *(const f32x4*)(xr + base);
  f32x4 b = *(const f32x4*)(xr + base + 4);
  float ss = a[0]*a[0] + a[1]*a[1] + a[2]*a[2] + a[3]*a[3]
           + b[0]*b[0] + b[1]*b[1] + b[2]*b[2] + b[3]*b[3];
  #pragma unroll
  for (int off = 1; off < 64; off <<= 1) ss += __shfl_xor(ss, off, 64);
  __shared__ float red[4];
  if ((threadIdx.x & 63) == 0) red[threadIdx.x >> 6] = ss;
  __syncthreads();
  float tot = red[0] + red[1] + red[2] + red[3];
  float rn = rsqrtf(tot * (1.0f / 2048.0f) + 1e-6f) * 0.022097086912079608f;
  f32x4 wa = *(const f32x4*)(w + base);
  f32x4 wb = *(const f32x4*)(w + base + 4);
  s16x8 o;
  #pragma unroll
  for (int j = 0; j < 4; ++j) {
    o[j]     = f2bf(a[j] * wa[j] * rn);
    o[4 + j] = f2bf(b[j] * wb[j] * rn);
  }
  *(s16x8*)(out + row * 2048 + base) = o;
}

// ---------------- small GEMM (kv proj only): 128x128 m97 structure ----------
template <int MODE>
__global__ __launch_bounds__(256, 2) void gemm_bt_kernel(
    const short* __restrict__ A, const short* __restrict__ B,
    void* __restrict__ Cv, const float* __restrict__ resid,
    int M, int N, int K)
{
  __shared__ short As[128 * 32];
  __shared__ short Bs[128 * 32];
  int tid = threadIdx.x;
  int lane = tid & 63;
  int w = tid >> 6;
  int r = lane & 15, g = lane >> 4;
  int wr = w >> 1, wc = w & 1;
  size_t row0 = (size_t)blockIdx.y * 128;
  size_t col0 = (size_t)blockIdx.x * 128;

  f32x4 acc[4][4];
  #pragma unroll
  for (int i = 0; i < 4; ++i)
    #pragma unroll
    for (int j = 0; j < 4; ++j) acc[i][j] = (f32x4){0.f, 0.f, 0.f, 0.f};

  const short* Ablk = A + row0 * K;
  const short* Bblk = B + col0 * K;
  int arow = tid >> 2;
  int akk = (tid & 3) << 3;

  for (int k0 = 0; k0 < K; k0 += 32) {
    #pragma unroll
    for (int i = 0; i < 2; ++i) {
      int chunk = i * 256 + tid;
      int rr = i * 64 + arow;
      __builtin_amdgcn_global_load_lds(
          (const __attribute__((address_space(1))) unsigned int*)(Ablk + (size_t)rr * K + k0 + akk),
          (__attribute__((address_space(3))) unsigned int*)(&As[chunk * 8]), 16, 0, 0);
      __builtin_amdgcn_global_load_lds(
          (const __attribute__((address_space(1))) unsigned int*)(Bblk + (size_t)rr * K + k0 + akk),
          (__attribute__((address_space(3))) unsigned int*)(&Bs[chunk * 8]), 16, 0, 0);
    }
    __syncthreads();
    s16x8 af[4], bfr[4];
    #pragma unroll
    for (int mm = 0; mm < 4; ++mm)
      af[mm] = *(const s16x8*)(&As[(wr * 64 + mm * 16 + r) * 32 + g * 8]);
    #pragma unroll
    for (int nn = 0; nn < 4; ++nn)
      bfr[nn] = *(const s16x8*)(&Bs[(wc * 64 + nn * 16 + r) * 32 + g * 8]);
    #pragma unroll
    for (int mm = 0; mm < 4; ++mm)
      #pragma unroll
      for (int nn = 0; nn < 4; ++nn)
        acc[mm][nn] = MFMA_BF16(af[mm], bfr[nn], acc[mm][nn], 0, 0, 0);
    __syncthreads();
  }

  #pragma unroll
  for (int mm = 0; mm < 4; ++mm) {
    #pragma unroll
    for (int nn = 0; nn < 4; ++nn) {
      #pragma unroll
      for (int j = 0; j < 4; ++j) {
        size_t rr = row0 + wr * 64 + mm * 16 + g * 4 + j;
        size_t cc = col0 + wc * 64 + nn * 16 + r;
        size_t idx = rr * (size_t)N + cc;
        if constexpr (MODE == 0) {
          ((short*)Cv)[idx] = f2bf(acc[mm][nn][j]);
        } else if constexpr (MODE == 1) {
          ((float*)Cv)[idx] = acc[mm][nn][j] + resid[idx];
        } else {
          short* gp = (short*)Cv;
          float gv = bf2f(gp[idx]);
          float sg = gv / (1.0f + __expf(-gv));
          gp[idx] = f2bf(sg * acc[mm][nn][j]);
        }
      }
    }
  }
}

// ---------------- 8-phase 256xBN GEMM (T1+T2+T3+T4+T5) ----------------------
// BM=256, BK=64 (2 K-halves of 32), 8 waves (2x4), 512 threads.
// Per phase: ds_read subtile | stage one half-tile (global_load_lds w16,
// pre-swizzled source, linear LDS dest) | barrier | MFMA | barrier.
// Counted vmcnt at phases 1 and 3 only; never 0 in main loop.
// LDS chunk swizzle: 16B-chunk c ^= (row>>1)&3 (both stage-source and read).

#define STAGEA(T, KH)                                                          \
  _Pragma("unroll")                                                            \
  for (int i = 0; i < 2; ++i) {                                                \
    int lc = i * 512 + tid;                                                    \
    int rw = lc >> 2, cp = lc & 3;                                             \
    __builtin_amdgcn_global_load_lds(                                          \
        (const __attribute__((address_space(1))) unsigned int*)                \
            (Ablk + (size_t)rw * K + (T) * 64 + (KH) * 32 +                    \
             ((cp ^ ((rw >> 1) & 3)) << 3)),                                   \
        (__attribute__((address_space(3))) unsigned int*)                      \
            (&As[(T) & 1][KH][lc * 8]), 16, 0, 0);                             \
  }

#define STAGEB(T, KH)                                                          \
  _Pragma("unroll")                                                            \
  for (int i = 0; i < BLOADS; ++i) {                                           \
    int lc = i * 512 + tid;                                                    \
    int rw = lc >> 2, cp = lc & 3;                                             \
    __builtin_amdgcn_global_load_lds(                                          \
        (const __attribute__((address_space(1))) unsigned int*)                \
            (Bblk + (size_t)rw * K + (T) * 64 + (KH) * 32 +                    \
             ((cp ^ ((rw >> 1) & 3)) << 3)),                                   \
        (__attribute__((address_space(3))) unsigned int*)                      \
            (&Bs[(T) & 1][KH][lc * 8]), 16, 0, 0);                             \
  }

#define LDA8(D, KH, MH)                                                        \
  _Pragma("unroll")                                                            \
  for (int mi = 0; mi < 4; ++mi) {                                             \
    int rowa = wr * 128 + ((MH) * 4 + mi) * 16 + r;                            \
    a[mi] = *(const s16x8*)(&As[D][KH][rowa * 32 + chsw * 8]);                 \
  }

#define LDB8(D, KH)                                                            \
  _Pragma("unroll")                                                            \
  for (int ni = 0; ni < NREP; ++ni) {                                          \
    int rowb = wc * WN + ni * 16 + r;                                          \
    b[ni] = *(const s16x8*)(&Bs[D][KH][rowb * 32 + chsw * 8]);                 \
  }

#define MF16(MH)                                                               \
  __builtin_amdgcn_s_setprio(1);                                               \
  _Pragma("unroll")                                                            \
  for (int mi = 0; mi < 4; ++mi)                                               \
    _Pragma("unroll")                                                          \
    for (int ni = 0; ni < NREP; ++ni)                                          \
      acc[(MH) * 4 + mi][ni] =                                                 \
          MFMA_BF16(a[mi], b[ni], acc[(MH) * 4 + mi][ni], 0, 0, 0);            \
  __builtin_amdgcn_s_setprio(0);

#define WAITC                                                                  \
  do {                                                                         \
    if constexpr (BN == 256)                                                   \
      asm volatile("s_waitcnt vmcnt(4)" ::: "memory");                         \
    else                                                                       \
      asm volatile("s_waitcnt vmcnt(3)" ::: "memory");                         \
  } while (0)

#define BAR __builtin_amdgcn_s_barrier()

template <int BN, int MODE>
__global__ __launch_bounds__(512, 2) void gemm8p_kernel(
    const short* __restrict__ A, const short* __restrict__ B,
    void* __restrict__ Cv, const float* __restrict__ resid,
    int M, int N, int K)
{
  constexpr int BLOADS = BN / 128;   // B-stage loads per thread per K-half
  constexpr int WN = BN / 4;         // per-wave output cols
  constexpr int NREP = WN / 16;
  __shared__ short As[2][2][256 * 32];
  __shared__ short Bs[2][2][BN * 32];

  int tid = threadIdx.x;
  int lane = tid & 63;
  int w = tid >> 6;
  int r = lane & 15, g = lane >> 4;
  int wr = w >> 2, wc = w & 3;
  int chsw = g ^ ((r >> 1) & 3);

  // bijective XCD swizzle (all grids here have nwg % 8 == 0)
  int nwg = gridDim.x * gridDim.y;
  int orig = blockIdx.y * gridDim.x + blockIdx.x;
  int swz = (orig & 7) * (nwg >> 3) + (orig >> 3);
  int bx = swz % gridDim.x, by = swz / gridDim.x;
  size_t row0 = (size_t)by * 256;
  size_t col0 = (size_t)bx * BN;

  const short* Ablk = A + row0 * K;
  const short* Bblk = B + col0 * K;

  f32x4 acc[8][NREP];
  #pragma unroll
  for (int i = 0; i < 8; ++i)
    #pragma unroll
    for (int j = 0; j < NREP; ++j) acc[i][j] = (f32x4){0.f, 0.f, 0.f, 0.f};

  s16x8 a[4], b[NREP];
  int NT = K >> 6;

  // prologue: stage tile 0 (queue order AK0, BK0, AK1, BK1), wait K0 halves
  STAGEA(0, 0); STAGEB(0, 0); STAGEA(0, 1); STAGEB(0, 1);
  WAITC;
  BAR;

  for (int t = 0; t < NT; ++t) {
    int d = t & 1;
    bool nl = (t < NT - 1);
    // phase 0: uses AK0,BK0 (ready); stage next AK0
    LDA8(d, 0, 0); LDB8(d, 0);
    if (nl) { STAGEA(t + 1, 0); }
    BAR;
    MF16(0);
    BAR;
    // phase 1: A ks0 m4-7; stage next BK0; wait -> curr AK1/BK1 ready
    LDA8(d, 0, 1);
    if (nl) { STAGEB(t + 1, 0); WAITC; }
    else    { asm volatile("s_waitcnt vmcnt(0)" ::: "memory"); }
    BAR;
    MF16(1);
    BAR;
    // phase 2: uses AK1,BK1; stage next AK1
    LDA8(d, 1, 0); LDB8(d, 1);
    if (nl) { STAGEA(t + 1, 1); }
    BAR;
    MF16(0);
    BAR;
    // phase 3: A ks1 m4-7; stage next BK1; wait -> next AK0/BK0 ready
    LDA8(d, 1, 1);
    if (nl) { STAGEB(t + 1, 1); WAITC; }
    BAR;
    MF16(1);
    BAR;
  }

  #pragma unroll
  for (int mi = 0; mi < 8; ++mi) {
    #pragma unroll
    for (int ni = 0; ni < NREP; ++ni) {
      #pragma unroll
      for (int j = 0; j < 4; ++j) {
        size_t rr = row0 + wr * 128 + mi * 16 + g * 4 + j;
        size_t cc = col0 + wc * WN + ni * 16 + r;
        size_t idx = rr * (size_t)N + cc;
        if constexpr (MODE == 0) {
          ((short*)Cv)[idx] = f2bf(acc[mi][ni][j]);
        } else if constexpr (MODE == 1) {
          ((float*)Cv)[idx] = acc[mi][ni][j] + resid[idx];
        } else {
          short* gp = (short*)Cv;
          float gv = bf2f(gp[idx]);
          float sg = gv / (1.0f + __expf(-gv));
          gp[idx] = f2bf(sg * acc[mi][ni][j]);
        }
      }
    }
  }
}

// ---------------- V transpose: kv[B*S,256] cols 128..255 -> [B][128][S] -----
__global__ __launch_bounds__(256) void transpose_v_kernel(
    const short* __restrict__ kv, short* __restrict__ vt)
{
  __shared__ short t[64][65];
  int b = blockIdx.z;
  int s0 = blockIdx.x * 64;
  int d0 = blockIdx.y * 64;
  int tid = threadIdx.x;
  #pragma unroll
  for (int i = 0; i < 16; ++i) {
    int e = i * 256 + tid;
    int sr = e >> 6, dc = e & 63;
    t[sr][dc] = kv[(size_t)(b * 2048 + s0 + sr) * 256 + 128 + d0 + dc];
  }
  __syncthreads();
  #pragma unroll
  for (int i = 0; i < 16; ++i) {
    int e = i * 256 + tid;
    int dr = e >> 6, sc = e & 63;
    vt[(size_t)b * 128 * 2048 + (size_t)(d0 + dr) * 2048 + s0 + sc] = t[sc][dr];
  }
}

// ---------------- Flash attention (MQA), LDS-staged K/V, 4 waves x 32 q-rows
__global__ __launch_bounds__(256, 2) void attn_kernel(
    const short* __restrict__ q, const short* __restrict__ kv,
    const short* __restrict__ vt, short* __restrict__ out)
{
  const int S = 2048;
  int tid = threadIdx.x;
  int w = tid >> 6;
  int lane = tid & 63;
  int r = lane & 15, g = lane >> 4;
  int h = blockIdx.y, b = blockIdx.z;
  int qrow0 = blockIdx.x * 128 + w * 32;

  __shared__ short Ks[2][4096];      // [32 kv][128 d], swizzled chunks
  __shared__ short Vs[2][4096];      // [128 d][32 kv], swizzled chunks
  __shared__ short Ps[4][32][40];    // per-wave P, padded

  const short* kvsrc = kv + (size_t)b * S * 256;        // K in cols 0..127
  const short* vsrc  = vt + (size_t)b * 128 * S;

  const short* qbase = q + ((size_t)(b * S + qrow0 + r)) * 2048 + h * 128;
  s16x8 qa[2][4];
  #pragma unroll
  for (int gq = 0; gq < 2; ++gq)
    #pragma unroll
    for (int dc = 0; dc < 4; ++dc)
      qa[gq][dc] = *(const s16x8*)(qbase + gq * 16 * 2048 + dc * 32 + g * 8);

  f32x4 o[2][8];
  #pragma unroll
  for (int gq = 0; gq < 2; ++gq)
    #pragma unroll
    for (int dt = 0; dt < 8; ++dt) o[gq][dt] = (f32x4){0.f, 0.f, 0.f, 0.f};
  float m[2][4], l[2][4];
  #pragma unroll
  for (int gq = 0; gq < 2; ++gq)
    #pragma unroll
    for (int j = 0; j < 4; ++j) { m[gq][j] = -1e30f; l[gq][j] = 0.f; }

#define STAGE(KVT, BSEL)                                                        \
  {                                                                             \
    int kv0s = (KVT) * 32;                                                      \
    _Pragma("unroll")                                                           \
    for (int i = 0; i < 2; ++i) {                                               \
      int c = w * 64 + lane + i * 256;                                          \
      int krow = c >> 4, kcp = c & 15;                                          \
      __builtin_amdgcn_global_load_lds(                                         \
          (const __attribute__((address_space(1))) unsigned int*)               \
              (kvsrc + (size_t)(kv0s + krow) * 256 + ((kcp ^ (krow & 7)) << 3)),\
          (__attribute__((address_space(3))) unsigned int*)(&Ks[BSEL][c * 8]),  \
          16, 0, 0);                                                            \
      int vrow = c >> 2, vcp = c & 3;                                           \
      __builtin_amdgcn_global_load_lds(                                         \
          (const __attribute__((address_space(1))) unsigned int*)               \
              (vsrc + (size_t)vrow * S + kv0s + ((vcp ^ (vrow & 3)) << 3)),     \
          (__attribute__((address_space(3))) unsigned int*)(&Vs[BSEL][c * 8]),  \
          16, 0, 0);                                                            \
    }                                                                           \
  }

  STAGE(0, 0);
  __syncthreads();

  for (int it = 0; it < 64; ++it) {
    int cur = it & 1;
    if (it < 63) STAGE(it + 1, cur ^ 1);

    s16x8 kc0[4], kc1[4], vb[8];
    #pragma unroll
    for (int dc = 0; dc < 4; ++dc) {
      kc0[dc] = *(const s16x8*)(&Ks[cur][r * 128 + (((dc * 4 + g) ^ (r & 7)) << 3)]);
      kc1[dc] = *(const s16x8*)(&Ks[cur][(16 + r) * 128 + (((dc * 4 + g) ^ (r & 7)) << 3)]);
    }
    #pragma unroll
    for (int dt = 0; dt < 8; ++dt)
      vb[dt] = *(const s16x8*)(&Vs[cur][(dt * 16 + r) * 32 + ((g ^ (r & 3)) << 3)]);

    f32x4 sc0[2], sc1[2];
    #pragma unroll
    for (int gq = 0; gq < 2; ++gq) { sc0[gq] = (f32x4){0.f,0.f,0.f,0.f}; sc1[gq] = (f32x4){0.f,0.f,0.f,0.f}; }
    __builtin_amdgcn_s_setprio(1);
    #pragma unroll
    for (int dc = 0; dc < 4; ++dc) {
      #pragma unroll
      for (int gq = 0; gq < 2; ++gq) {
        sc0[gq] = MFMA_BF16(qa[gq][dc], kc0[dc], sc0[gq], 0, 0, 0);
        sc1[gq] = MFMA_BF16(qa[gq][dc], kc1[dc], sc1[gq], 0, 0, 0);
      }
    }
    __builtin_amdgcn_s_setprio(0);

    float p0[2][4], p1[2][4];
    #pragma unroll
    for (int gq = 0; gq < 2; ++gq) {
      float mx[4];
      #pragma unroll
      for (int j = 0; j < 4; ++j) mx[j] = rowmax16(fmaxf(sc0[gq][j], sc1[gq][j]));
      bool nd = (mx[0] > m[gq][0] + 8.f) | (mx[1] > m[gq][1] + 8.f)
              | (mx[2] > m[gq][2] + 8.f) | (mx[3] > m[gq][3] + 8.f);
      if (__any(nd)) {
        #pragma unroll
        for (int j = 0; j < 4; ++j) {
          float mn = fmaxf(m[gq][j], mx[j]);
          float alpha = __expf(m[gq][j] - mn);
          m[gq][j] = mn;
          l[gq][j] *= alpha;
          #pragma unroll
          for (int dt = 0; dt < 8; ++dt) o[gq][dt][j] *= alpha;
        }
      }
      #pragma unroll
      for (int j = 0; j < 4; ++j) {
        p0[gq][j] = __expf(sc0[gq][j] - m[gq][j]);
        p1[gq][j] = __expf(sc1[gq][j] - m[gq][j]);
        l[gq][j] += p0[gq][j] + p1[gq][j];
      }
      #pragma unroll
      for (int j = 0; j < 4; ++j) {
        Ps[w][gq * 16 + g * 4 + j][r]      = f2bf(p0[gq][j]);
        Ps[w][gq * 16 + g * 4 + j][16 + r] = f2bf(p1[gq][j]);
      }
    }
    asm volatile("s_waitcnt lgkmcnt(0)" ::: "memory");
    __builtin_amdgcn_sched_barrier(0);
    s16x8 pa0 = *(const s16x8*)(&Ps[w][r][g * 8]);
    s16x8 pa1 = *(const s16x8*)(&Ps[w][16 + r][g * 8]);
    __builtin_amdgcn_s_setprio(1);
    #pragma unroll
    for (int dt = 0; dt < 8; ++dt) {
      o[0][dt] = MFMA_BF16(pa0, vb[dt], o[0][dt], 0, 0, 0);
      o[1][dt] = MFMA_BF16(pa1, vb[dt], o[1][dt], 0, 0, 0);
    }
    __builtin_amdgcn_s_setprio(0);
    __syncthreads();
  }

  #pragma unroll
  for (int gq = 0; gq < 2; ++gq) {
    float linv[4];
    #pragma unroll
    for (int j = 0; j < 4; ++j) linv[j] = 1.0f / rowsum16(l[gq][j]);
    short* ob = out + ((size_t)(b * S + qrow0 + gq * 16)) * 2048 + h * 128;
    #pragma unroll
    for (int dt = 0; dt < 8; ++dt)
      #pragma unroll
      for (int j = 0; j < 4; ++j)
        ob[(size_t)(g * 4 + j) * 2048 + dt * 16 + r] = f2bf(o[gq][dt][j] * linv[j]);
  }
#undef STAGE
}

extern "C" void kernel_launch(void* const* d_in, const int* in_sizes, int n_in,
                              void* d_out, int out_size, void* d_ws, size_t ws_size,
                              hipStream_t stream) {
  const float* x   = (const float*)d_in[0];
  const float* n1w = (const float*)d_in[1];
  const float* wq  = (const float*)d_in[2];
  const float* wk  = (const float*)d_in[3];
  const float* wv  = (const float*)d_in[4];
  const float* wo  = (const float*)d_in[5];
  const float* n2w = (const float*)d_in[6];
  const float* w1  = (const float*)d_in[7];
  const float* w2  = (const float*)d_in[8];
  const float* w3  = (const float*)d_in[9];
  float* out = (float*)d_out;   // doubles as fp32 xmid buffer
  char* ws = (char*)d_ws;
  const size_t MB = 1ull << 20;
  short* wqb  = (short*)(ws);              //  8 MB (pre-scaled by 1/sqrt(128))
  short* wob  = (short*)(ws + 8 * MB);     //  8 MB
  short* w1b  = (short*)(ws + 16 * MB);    // 32 MB
  short* w2b  = (short*)(ws + 48 * MB);    // 32 MB
  short* w3b  = (short*)(ws + 80 * MB);    // 32 MB
  short* wkvb = (short*)(ws + 112 * MB);   //  1 MB [256,2048]
  short* h1   = (short*)(ws + 113 * MB);   // 16 MB
  short* gbuf = (short*)(ws + 129 * MB);   // 64 MB; overlays qb/kvb/vtb
  short* qb   = (short*)(ws + 129 * MB);   // 16 MB
  short* kvb  = (short*)(ws + 145 * MB);   //  2 MB
  short* vtb  = (short*)(ws + 147 * MB);   //  1 MB

  const float qscale = 0.08838834764831845f;  // 1/sqrt(128) folded into wq
  cvt_kernel<<<2048, 256, 0, stream>>>(wq, wqb, 4194304, qscale);
  cvt_kernel<<<128,  256, 0, stream>>>(wk, wkvb, 262144, 1.0f);
  cvt_kernel<<<128,  256, 0, stream>>>(wv, wkvb + 262144, 262144, 1.0f);
  cvt_kernel<<<2048, 256, 0, stream>>>(wo, wob, 4194304, 1.0f);
  cvt_kernel<<<8192, 256, 0, stream>>>(w1, w1b, 16777216, 1.0f);
  cvt_kernel<<<8192, 256, 0, stream>>>(w2, w2b, 16777216, 1.0f);
  cvt_kernel<<<8192, 256, 0, stream>>>(w3, w3b, 16777216, 1.0f);

  rmsnorm_kernel<<<4096, 256, 0, stream>>>(x, n1w, h1);
  gemm8p_kernel<128, 0><<<dim3(16, 16), 512, 0, stream>>>(h1, wqb, qb, nullptr, 4096, 2048, 2048);
  gemm_bt_kernel<0><<<dim3(2, 32), 256, 0, stream>>>(h1, wkvb, kvb, nullptr, 4096, 256, 2048);
  transpose_v_kernel<<<dim3(32, 2, 2), 256, 0, stream>>>(kvb, vtb);
  attn_kernel<<<dim3(16, 16, 2), 256, 0, stream>>>(qb, kvb, vtb, h1);
  gemm8p_kernel<128, 1><<<dim3(16, 16), 512, 0, stream>>>(h1, wob, out, x, 4096, 2048, 2048);
  rmsnorm_kernel<<<4096, 256, 0, stream>>>(out, n2w, h1);
  gemm8p_kernel<256, 0><<<dim3(32, 16), 512, 0, stream>>>(h1, w1b, gbuf, nullptr, 4096, 8192, 2048);
  gemm8p_kernel<256, 2><<<dim3(32, 16), 512, 0, stream>>>(h1, w3b, gbuf, nullptr, 4096, 8192, 2048);
  gemm8p_kernel<128, 1><<<dim3(16, 16), 512, 0, stream>>>(gbuf, w2b, out, out, 4096, 2048, 8192);
}